// Round 6
// baseline (823.059 us; speedup 1.0000x reference)
//
#include <hip/hip_runtime.h>

#define N_NODES   50000
#define N_EDGES   1600000
#define DDIM      64
#define N_GRAPHS  512
#define N_CLASSES 53
#define ITERS     3
#define NB        782            // ceil(N_NODES/64) buckets of 64 dst nodes
#define NPB       128            // partition blocks
#define CHUNK     ((N_EDGES + NPB - 1) / NPB)

typedef __bf16 bf16x8 __attribute__((ext_vector_type(8)));
typedef float  f32x4  __attribute__((ext_vector_type(4)));

// h[node][d] = emb[pkt[node]][d], float4-vectorized
__global__ void embed_kernel(const int* __restrict__ pkt, const float4* __restrict__ emb,
                             float4* __restrict__ h) {
  int idx = blockIdx.x * 256 + threadIdx.x;
  if (idx >= N_NODES * 16) return;
  int node = idx >> 4;
  h[idx] = emb[(size_t)pkt[node] * 16 + (idx & 15)];
}

// edge-count per 64-node dst bucket, LDS-staged
__global__ void bucket_hist_kernel(const int* __restrict__ dst, int* __restrict__ bhist) {
  __shared__ int lh[NB];
  for (int i = threadIdx.x; i < NB; i += 256) lh[i] = 0;
  __syncthreads();
  int stride = gridDim.x * 256;
  for (int e = blockIdx.x * 256 + threadIdx.x; e < N_EDGES; e += stride)
    atomicAdd(&lh[dst[e] >> 6], 1);
  __syncthreads();
  for (int i = threadIdx.x; i < NB; i += 256)
    if (lh[i]) atomicAdd(&bhist[i], lh[i]);
}

__global__ void hist_kernel(const int* __restrict__ idx, int* __restrict__ counts, int n) {
  int i = blockIdx.x * 256 + threadIdx.x;
  if (i < n) atomicAdd(&counts[idx[i]], 1);
}

// single-block exclusive scan; offs[n] = total; optional cursor copy
__global__ void scan_kernel(const int* __restrict__ counts, int* __restrict__ offs,
                            int* __restrict__ cursor, int n) {
  __shared__ int wsum[16];
  __shared__ int carry;
  int tid = threadIdx.x;               // 1024 threads
  if (tid == 0) carry = 0;
  __syncthreads();
  for (int base = 0; base < n; base += 1024) {
    int i = base + tid;
    int v = (i < n) ? counts[i] : 0;
    int x = v;
    #pragma unroll
    for (int off = 1; off < 64; off <<= 1) {
      int y = __shfl_up(x, off);
      if ((tid & 63) >= off) x += y;
    }
    int w = tid >> 6;
    if ((tid & 63) == 63) wsum[w] = x;
    __syncthreads();
    int woff = 0;
    for (int k = 0; k < w; ++k) woff += wsum[k];
    int incl = x + woff + carry;
    if (i < n) {
      offs[i] = incl - v;
      if (cursor) cursor[i] = incl - v;
    }
    __syncthreads();
    if (tid == 1023) carry = incl;
    __syncthreads();
  }
  if (tid == 0) offs[n] = carry;
}

// bucket-partition edges: ebuf[pos] = src(16b) | (dst&63)<<16, grouped by dst>>6
__global__ void partition_kernel(const int* __restrict__ src, const int* __restrict__ dst,
                                 int* __restrict__ bcursor, unsigned* __restrict__ ebuf) {
  __shared__ int lh[NB];
  __shared__ int lbase[NB];
  for (int i = threadIdx.x; i < NB; i += 256) lh[i] = 0;
  __syncthreads();
  int e0 = blockIdx.x * CHUNK;
  int e1 = min(e0 + CHUNK, N_EDGES);
  for (int e = e0 + (int)threadIdx.x; e < e1; e += 256)
    atomicAdd(&lh[dst[e] >> 6], 1);
  __syncthreads();
  for (int i = threadIdx.x; i < NB; i += 256) {
    int c = lh[i];
    lbase[i] = c ? atomicAdd(&bcursor[i], c) : 0;
    lh[i] = 0;                         // reuse as running cursor
  }
  __syncthreads();
  for (int e = e0 + (int)threadIdx.x; e < e1; e += 256) {
    int d = dst[e];
    int b = d >> 6;
    int pos = lbase[b] + atomicAdd(&lh[b], 1);
    ebuf[pos] = (unsigned)src[e] | ((unsigned)(d & 63) << 16);
  }
}

// block per bucket: per-node offsets (in-block 64-scan) + CSR scatter locally
__global__ __launch_bounds__(256) void local_scatter_kernel(
    const unsigned* __restrict__ ebuf, const int* __restrict__ boffs,
    int* __restrict__ offs, int* __restrict__ csr) {
  __shared__ int cnt[64];
  __shared__ int base[64];
  const int b = blockIdx.x;
  const int tid = threadIdx.x;
  if (tid < 64) cnt[tid] = 0;
  __syncthreads();
  const int ebeg = boffs[b], eend = boffs[b + 1];
  for (int e = ebeg + tid; e < eend; e += 256)
    atomicAdd(&cnt[(ebuf[e] >> 16) & 63u], 1);
  __syncthreads();
  if (tid < 64) {                      // wave 0: exclusive scan of 64 counts
    int v = cnt[tid];
    int x = v;
    #pragma unroll
    for (int off = 1; off < 64; off <<= 1) {
      int y = __shfl_up(x, off);
      if (tid >= off) x += y;
    }
    int excl = ebeg + x - v;
    base[tid] = excl;
    int node = b * 64 + tid;
    if (node < N_NODES) offs[node] = excl;
    cnt[tid] = 0;                      // reuse as running cursor
  }
  __syncthreads();
  for (int e = ebeg + tid; e < eend; e += 256) {
    unsigned p = ebuf[e];
    int j = (p >> 16) & 63u;
    int pos = base[j] + atomicAdd(&cnt[j], 1);
    csr[pos] = (int)(p & 0xFFFFu);
  }
  if (b == NB - 1 && tid == 0) offs[N_NODES] = N_EDGES;
}

// x[v] = (1+eps)*h[v] + sum_{u in in-nbrs(v)} h[u]; wave per node, lane = feature
__global__ void aggregate_kernel(const float* __restrict__ h, const int* __restrict__ offs,
                                 const int* __restrict__ csr, const float* __restrict__ epsp,
                                 float* __restrict__ x) {
  int node = blockIdx.x * 4 + (threadIdx.x >> 6);
  if (node >= N_NODES) return;
  int lane = threadIdx.x & 63;
  int beg = offs[node], end = offs[node + 1];
  float acc = (1.0f + epsp[0]) * h[(size_t)node * DDIM + lane];
  int e = beg;
  for (; e + 8 <= end; e += 8) {       // 8 gathers in flight (latency-bound)
    int u[8];
    #pragma unroll
    for (int q = 0; q < 8; ++q) u[q] = csr[e + q];
    float a[8];
    #pragma unroll
    for (int q = 0; q < 8; ++q) a[q] = h[(size_t)u[q] * DDIM + lane];
    acc += ((a[0] + a[1]) + (a[2] + a[3])) + ((a[4] + a[5]) + (a[6] + a[7]));
  }
  for (; e < end; ++e) acc += h[(size_t)csr[e] * DDIM + lane];
  x[(size_t)node * DDIM + lane] = acc;
}

// pack W1,W2,W3 into MFMA B-fragment order, SPLIT bf16: hi=bf16(w), lo=bf16(w-hi).
// frag f = (L*2 + kc)*4 + t; lane l holds W[kc*32 + (l>>4)*8 + e][t*16 + (l&15)]
// wbuf[f*64+lane] = hi frags; wbuf[1536 + f*64+lane] = lo frags
__global__ void pack_weights_kernel(const float* __restrict__ W1, const float* __restrict__ W2,
                                    const float* __restrict__ W3, bf16x8* __restrict__ wbuf) {
  int i = blockIdx.x * 256 + threadIdx.x;
  if (i >= 24 * 64) return;
  int lane = i & 63;
  int frag = i >> 6;
  int t = frag & 3;
  int kc = (frag >> 2) & 1;
  int L = frag >> 3;
  const float* W = (L == 0) ? W1 : ((L == 1) ? W2 : W3);
  int l15 = lane & 15, lg = lane >> 4;
  bf16x8 fh, fl;
  #pragma unroll
  for (int e = 0; e < 8; ++e) {
    int k = kc * 32 + lg * 8 + e;
    float w = W[k * 64 + t * 16 + l15];
    __bf16 hi = (__bf16)w;
    fh[e] = hi;
    fl[e] = (__bf16)(w - (float)hi);
  }
  wbuf[i] = fh;
  wbuf[24 * 64 + i] = fl;
}

__device__ __forceinline__ void split8(const f32x4& v0, const f32x4& v1,
                                       bf16x8& hi, bf16x8& lo) {
  #pragma unroll
  for (int e = 0; e < 4; ++e) {
    __bf16 h0 = (__bf16)v0[e];
    __bf16 h1 = (__bf16)v1[e];
    hi[e] = h0;     lo[e] = (__bf16)(v0[e] - (float)h0);
    hi[4 + e] = h1; lo[4 + e] = (__bf16)(v1[e] - (float)h1);
  }
}

#define MFMA(A, B, C) __builtin_amdgcn_mfma_f32_16x16x32_bf16((A), (B), (C), 0, 0, 0)

// one output col-tile T of layer L: 3-term split-bf16 product, all names literal.
// Live B-frags: 4 (16 VGPRs). ACC is a named f32x4.
#define DOT(L, T, BIASV, ACC)                                        \
  {                                                                  \
    bf16x8 bh0 = wbuf[(((L) * 2 + 0) * 4 + (T)) * 64 + lane];        \
    bf16x8 bh1 = wbuf[(((L) * 2 + 1) * 4 + (T)) * 64 + lane];        \
    bf16x8 bl0 = wbuf[1536 + (((L) * 2 + 0) * 4 + (T)) * 64 + lane]; \
    bf16x8 bl1 = wbuf[1536 + (((L) * 2 + 1) * 4 + (T)) * 64 + lane]; \
    f32x4 a_ = {(BIASV), (BIASV), (BIASV), (BIASV)};                 \
    a_ = MFMA(A0h, bh0, a_);                                         \
    a_ = MFMA(A1h, bh1, a_);                                         \
    a_ = MFMA(A0l, bh0, a_);                                         \
    a_ = MFMA(A1l, bh1, a_);                                         \
    a_ = MFMA(A0h, bl0, a_);                                         \
    a_ = MFMA(A1h, bl1, a_);                                         \
    ACC = a_;                                                        \
  }

#define DOLAYER(L)                   \
  DOT(L, 0, bias##L[0], acc0)        \
  DOT(L, 1, bias##L[1], acc1)        \
  DOT(L, 2, bias##L[2], acc2)        \
  DOT(L, 3, bias##L[3], acc3)

// relu(acc) -> per-wave LDS scratch (pitch 68), literal element indices
#define STORE_T(T, A)                                         \
  sc[(4 * lg + 0) * 68 + (T) * 16 + l15] = fmaxf(A[0], 0.f);  \
  sc[(4 * lg + 1) * 68 + (T) * 16 + l15] = fmaxf(A[1], 0.f);  \
  sc[(4 * lg + 2) * 68 + (T) * 16 + l15] = fmaxf(A[2], 0.f);  \
  sc[(4 * lg + 3) * 68 + (T) * 16 + l15] = fmaxf(A[3], 0.f);

#define TRANSITION                                            \
  {                                                           \
    STORE_T(0, acc0)                                          \
    STORE_T(1, acc1)                                          \
    STORE_T(2, acc2)                                          \
    STORE_T(3, acc3)                                          \
    const float* rp = sc + l15 * 68 + lg * 8;                 \
    f32x4 r0 = *(const f32x4*)(rp);                           \
    f32x4 r1 = *(const f32x4*)(rp + 4);                       \
    f32x4 r2 = *(const f32x4*)(rp + 32);                      \
    f32x4 r3 = *(const f32x4*)(rp + 36);                      \
    split8(r0, r1, A0h, A0l);                                 \
    split8(r2, r3, A1h, A1l);                                 \
  }

// epilogue col-tile: relu, store f32, BN partials (literal indices throughout)
#define EPI_T(T, A)                                                       \
  {                                                                       \
    float v0 = fmaxf(A[0], 0.f), v1 = fmaxf(A[1], 0.f);                   \
    float v2 = fmaxf(A[2], 0.f), v3 = fmaxf(A[3], 0.f);                   \
    xout[(size_t)(rows0 + 4 * lg + 0) * DDIM + (T) * 16 + l15] = v0;      \
    xout[(size_t)(rows0 + 4 * lg + 1) * DDIM + (T) * 16 + l15] = v1;      \
    xout[(size_t)(rows0 + 4 * lg + 2) * DDIM + (T) * 16 + l15] = v2;      \
    xout[(size_t)(rows0 + 4 * lg + 3) * DDIM + (T) * 16 + l15] = v3;      \
    float vs = (v0 + v1) + (v2 + v3);                                     \
    float vq = ((v0 * v0 + v1 * v1) + (v2 * v2 + v3 * v3));               \
    vs += __shfl_xor(vs, 16); vs += __shfl_xor(vs, 32);                   \
    vq += __shfl_xor(vq, 16); vq += __shfl_xor(vq, 32);                   \
    if (lane < 16) {                                                      \
      atomicAdd(&bnsum[(T) * 16 + l15], vs);                              \
      atomicAdd(&bnsq[(T) * 16 + l15], vq);                               \
    }                                                                     \
  }

// MFMA MLP: wave per 16-row tile; split-bf16 in, f32 accum; fused bias/relu/BN-stats
__global__ __launch_bounds__(256) void mlp_kernel(
    const float* __restrict__ xin, float* __restrict__ xout,
    const bf16x8* __restrict__ wbuf,
    const float* __restrict__ b1, const float* __restrict__ b2, const float* __restrict__ b3,
    float* __restrict__ bnsum, float* __restrict__ bnsq) {
  __shared__ float scratch[4][16 * 68];
  const int tid = threadIdx.x;
  const int lane = tid & 63, wave = tid >> 6;
  const int l15 = lane & 15, lg = lane >> 4;
  const int rows0 = blockIdx.x * 64 + wave * 16;
  if (rows0 >= N_NODES) return;       // no __syncthreads below: early-out safe
  float* sc = scratch[wave];

  float bias0[4], bias1[4], bias2[4];
  #pragma unroll
  for (int t = 0; t < 4; ++t) {
    bias0[t] = b1[t * 16 + l15];
    bias1[t] = b2[t * 16 + l15];
    bias2[t] = b3[t * 16 + l15];
  }

  // layer-1 A fragments straight from global (rows L2/L3-resident)
  const float* xrow = xin + (size_t)(rows0 + l15) * DDIM;
  bf16x8 A0h, A0l, A1h, A1l;
  {
    f32x4 v0 = *(const f32x4*)(xrow + lg * 8);
    f32x4 v1 = *(const f32x4*)(xrow + lg * 8 + 4);
    f32x4 v2 = *(const f32x4*)(xrow + 32 + lg * 8);
    f32x4 v3 = *(const f32x4*)(xrow + 32 + lg * 8 + 4);
    split8(v0, v1, A0h, A0l);
    split8(v2, v3, A1h, A1l);
  }

  f32x4 acc0, acc1, acc2, acc3;
  DOLAYER(0)
  TRANSITION
  DOLAYER(1)
  TRANSITION
  DOLAYER(2)

  EPI_T(0, acc0)
  EPI_T(1, acc1)
  EPI_T(2, acc2)
  EPI_T(3, acc3)
}

__global__ void bn_finalize_kernel(float* __restrict__ bnsum, float* __restrict__ bnsq,
                                   float* __restrict__ stats) {
  int lane = threadIdx.x;              // 64 threads
  const float invN = 1.0f / N_NODES;
  float m = bnsum[lane] * invN;
  float var = bnsq[lane] * invN - m * m;
  stats[lane] = m;
  stats[64 + lane] = 1.0f / sqrtf(var + 1e-5f);
  bnsum[lane] = 0.f;                   // ready for next iteration
  bnsq[lane] = 0.f;
}

// BN-apply -> h, plus atomic-free graph pooling (block per graph; graph_ids sorted)
__global__ void norm_pool_kernel(const float* __restrict__ x, float* __restrict__ h,
                                 float* __restrict__ pooled, const int* __restrict__ goff,
                                 const float* __restrict__ stats, const float* __restrict__ gamma,
                                 const float* __restrict__ beta, int iter) {
  int g = blockIdx.x;
  int lane = threadIdx.x & 63;
  int wave = threadIdx.x >> 6;
  float mean = stats[lane];
  float inv = stats[64 + lane];
  float gm = gamma[lane] * inv;
  float bt = beta[lane] - mean * gm;   // h = gm*v + bt
  int rbeg = goff[g], rend = goff[g + 1];
  float acc = 0.f;
  for (int r = rbeg + wave; r < rend; r += 4) {
    float v = fmaf(x[(size_t)r * DDIM + lane], gm, bt);
    h[(size_t)r * DDIM + lane] = v;
    acc += v;
  }
  __shared__ float red[4][64];
  red[wave][lane] = acc;
  __syncthreads();
  if (wave == 0) {
    pooled[(size_t)g * (ITERS * DDIM) + iter * DDIM + lane] =
        red[0][lane] + red[1][lane] + red[2][lane] + red[3][lane];
  }
}

__global__ void classifier_kernel(const float* __restrict__ pooled, const float* __restrict__ Wc,
                                  const float* __restrict__ bc, float* __restrict__ out) {
  int g = blockIdx.x;
  int c = threadIdx.x;
  if (c >= N_CLASSES) return;
  float acc = bc[c];
  #pragma unroll 4
  for (int k = 0; k < ITERS * DDIM; ++k)
    acc = fmaf(pooled[(size_t)g * (ITERS * DDIM) + k], Wc[k * N_CLASSES + c], acc);
  out[(size_t)g * N_CLASSES + c] = acc;
}

extern "C" void kernel_launch(void* const* d_in, const int* in_sizes, int n_in,
                              void* d_out, int out_size, void* d_ws, size_t ws_size,
                              hipStream_t stream) {
  const int*   pkt   = (const int*)d_in[0];
  const int*   src   = (const int*)d_in[1];
  const int*   dst   = (const int*)d_in[2];
  const int*   gids  = (const int*)d_in[3];
  const float* emb   = (const float*)d_in[4];
  const float* eps   = (const float*)d_in[5];
  const float* W1    = (const float*)d_in[6];
  const float* b1    = (const float*)d_in[7];
  const float* W2    = (const float*)d_in[8];
  const float* b2    = (const float*)d_in[9];
  const float* W3    = (const float*)d_in[10];
  const float* b3    = (const float*)d_in[11];
  const float* gamma = (const float*)d_in[12];
  const float* beta  = (const float*)d_in[13];
  const float* Wc    = (const float*)d_in[14];
  const float* bc    = (const float*)d_in[15];
  float* out = (float*)d_out;

  char* p = (char*)d_ws;
  auto alloc = [&](size_t bytes) {
    char* r = p;
    p += (bytes + 255) & ~(size_t)255;
    return r;
  };
  float*    h       = (float*)alloc((size_t)N_NODES * DDIM * 4);
  float*    x       = (float*)alloc((size_t)N_NODES * DDIM * 4);
  unsigned* ebuf    = (unsigned*)alloc((size_t)N_EDGES * 4);
  int*      csr     = (int*)alloc((size_t)N_EDGES * 4);
  int*      offs    = (int*)alloc((size_t)(N_NODES + 1) * 4);
  int*      boffs   = (int*)alloc((size_t)(NB + 1) * 4);
  int*      bcursor = (int*)alloc((size_t)NB * 4);
  int*      goff    = (int*)alloc((size_t)(N_GRAPHS + 1) * 4);
  float*    pooled  = (float*)alloc((size_t)N_GRAPHS * ITERS * DDIM * 4);
  float*    stats   = (float*)alloc(128 * 4);
  bf16x8*   wbuf    = (bf16x8*)alloc((size_t)48 * 64 * 16);   // hi + lo fragments
  // contiguous zero region: bhist | gcnt | bnsum | bnsq
  size_t zbytes = (size_t)NB * 4 + (size_t)N_GRAPHS * 4 + 512;
  char*  zbase  = alloc(zbytes);
  int*   bhist  = (int*)zbase;
  int*   gcnt   = bhist + NB;
  float* bnsum  = (float*)(gcnt + N_GRAPHS);
  float* bnsq   = bnsum + 64;

  hipMemsetAsync(zbase, 0, zbytes, stream);

  embed_kernel<<<(N_NODES * 16 + 255) / 256, 256, 0, stream>>>(pkt, (const float4*)emb,
                                                               (float4*)h);
  bucket_hist_kernel<<<256, 256, 0, stream>>>(dst, bhist);
  hist_kernel<<<(N_NODES + 255) / 256, 256, 0, stream>>>(gids, gcnt, N_NODES);
  scan_kernel<<<1, 1024, 0, stream>>>(bhist, boffs, bcursor, NB);
  scan_kernel<<<1, 1024, 0, stream>>>(gcnt, goff, nullptr, N_GRAPHS);
  partition_kernel<<<NPB, 256, 0, stream>>>(src, dst, bcursor, ebuf);
  local_scatter_kernel<<<NB, 256, 0, stream>>>(ebuf, boffs, offs, csr);
  pack_weights_kernel<<<6, 256, 0, stream>>>(W1, W2, W3, wbuf);

  for (int it = 0; it < ITERS; ++it) {
    aggregate_kernel<<<(N_NODES + 3) / 4, 256, 0, stream>>>(h, offs, csr, eps, x);
    mlp_kernel<<<NB, 256, 0, stream>>>(x, x, wbuf, b1, b2, b3, bnsum, bnsq);
    bn_finalize_kernel<<<1, 64, 0, stream>>>(bnsum, bnsq, stats);
    norm_pool_kernel<<<N_GRAPHS, 256, 0, stream>>>(x, h, pooled, goff, stats, gamma, beta, it);
  }
  classifier_kernel<<<N_GRAPHS, 64, 0, stream>>>(pooled, Wc, bc, out);
}

// Round 7
// 665.195 us; speedup vs baseline: 1.2373x; 1.2373x over previous
//
#include <hip/hip_runtime.h>

#define N_NODES   50000
#define N_EDGES   1600000
#define DDIM      64
#define N_GRAPHS  512
#define N_CLASSES 53
#define ITERS     3
#define NB        782            // ceil(N_NODES/64) buckets of 64 dst nodes
#define NPB       128            // partition blocks
#define CHUNK     ((N_EDGES + NPB - 1) / NPB)

typedef __bf16 bf16x8 __attribute__((ext_vector_type(8)));
typedef float  f32x4  __attribute__((ext_vector_type(4)));

// h[node][d] = emb[pkt[node]][d], float4-vectorized
__global__ void embed_kernel(const int* __restrict__ pkt, const float4* __restrict__ emb,
                             float4* __restrict__ h) {
  int idx = blockIdx.x * 256 + threadIdx.x;
  if (idx >= N_NODES * 16) return;
  int node = idx >> 4;
  h[idx] = emb[(size_t)pkt[node] * 16 + (idx & 15)];
}

// edge-count per 64-node dst bucket, LDS-staged
__global__ void bucket_hist_kernel(const int* __restrict__ dst, int* __restrict__ bhist) {
  __shared__ int lh[NB];
  for (int i = threadIdx.x; i < NB; i += 256) lh[i] = 0;
  __syncthreads();
  int stride = gridDim.x * 256;
  for (int e = blockIdx.x * 256 + threadIdx.x; e < N_EDGES; e += stride)
    atomicAdd(&lh[dst[e] >> 6], 1);
  __syncthreads();
  for (int i = threadIdx.x; i < NB; i += 256)
    if (lh[i]) atomicAdd(&bhist[i], lh[i]);
}

__global__ void hist_kernel(const int* __restrict__ idx, int* __restrict__ counts, int n) {
  int i = blockIdx.x * 256 + threadIdx.x;
  if (i < n) atomicAdd(&counts[idx[i]], 1);
}

// single-block exclusive scan; offs[n] = total; optional cursor copy
__global__ void scan_kernel(const int* __restrict__ counts, int* __restrict__ offs,
                            int* __restrict__ cursor, int n) {
  __shared__ int wsum[16];
  __shared__ int carry;
  int tid = threadIdx.x;               // 1024 threads
  if (tid == 0) carry = 0;
  __syncthreads();
  for (int base = 0; base < n; base += 1024) {
    int i = base + tid;
    int v = (i < n) ? counts[i] : 0;
    int x = v;
    #pragma unroll
    for (int off = 1; off < 64; off <<= 1) {
      int y = __shfl_up(x, off);
      if ((tid & 63) >= off) x += y;
    }
    int w = tid >> 6;
    if ((tid & 63) == 63) wsum[w] = x;
    __syncthreads();
    int woff = 0;
    for (int k = 0; k < w; ++k) woff += wsum[k];
    int incl = x + woff + carry;
    if (i < n) {
      offs[i] = incl - v;
      if (cursor) cursor[i] = incl - v;
    }
    __syncthreads();
    if (tid == 1023) carry = incl;
    __syncthreads();
  }
  if (tid == 0) offs[n] = carry;
}

// bucket-partition edges: ebuf[pos] = src(16b) | (dst&63)<<16, grouped by dst>>6
__global__ void partition_kernel(const int* __restrict__ src, const int* __restrict__ dst,
                                 int* __restrict__ bcursor, unsigned* __restrict__ ebuf) {
  __shared__ int lh[NB];
  __shared__ int lbase[NB];
  for (int i = threadIdx.x; i < NB; i += 256) lh[i] = 0;
  __syncthreads();
  int e0 = blockIdx.x * CHUNK;
  int e1 = min(e0 + CHUNK, N_EDGES);
  for (int e = e0 + (int)threadIdx.x; e < e1; e += 256)
    atomicAdd(&lh[dst[e] >> 6], 1);
  __syncthreads();
  for (int i = threadIdx.x; i < NB; i += 256) {
    int c = lh[i];
    lbase[i] = c ? atomicAdd(&bcursor[i], c) : 0;
    lh[i] = 0;                         // reuse as running cursor
  }
  __syncthreads();
  for (int e = e0 + (int)threadIdx.x; e < e1; e += 256) {
    int d = dst[e];
    int b = d >> 6;
    int pos = lbase[b] + atomicAdd(&lh[b], 1);
    ebuf[pos] = (unsigned)src[e] | ((unsigned)(d & 63) << 16);
  }
}

// block per bucket: per-node offsets (in-block 64-scan) + CSR scatter locally
__global__ __launch_bounds__(256) void local_scatter_kernel(
    const unsigned* __restrict__ ebuf, const int* __restrict__ boffs,
    int* __restrict__ offs, int* __restrict__ csr) {
  __shared__ int cnt[64];
  __shared__ int base[64];
  const int b = blockIdx.x;
  const int tid = threadIdx.x;
  if (tid < 64) cnt[tid] = 0;
  __syncthreads();
  const int ebeg = boffs[b], eend = boffs[b + 1];
  for (int e = ebeg + tid; e < eend; e += 256)
    atomicAdd(&cnt[(ebuf[e] >> 16) & 63u], 1);
  __syncthreads();
  if (tid < 64) {                      // wave 0: exclusive scan of 64 counts
    int v = cnt[tid];
    int x = v;
    #pragma unroll
    for (int off = 1; off < 64; off <<= 1) {
      int y = __shfl_up(x, off);
      if (tid >= off) x += y;
    }
    int excl = ebeg + x - v;
    base[tid] = excl;
    int node = b * 64 + tid;
    if (node < N_NODES) offs[node] = excl;
    cnt[tid] = 0;                      // reuse as running cursor
  }
  __syncthreads();
  for (int e = ebeg + tid; e < eend; e += 256) {
    unsigned p = ebuf[e];
    int j = (p >> 16) & 63u;
    int pos = base[j] + atomicAdd(&cnt[j], 1);
    csr[pos] = (int)(p & 0xFFFFu);
  }
  if (b == NB - 1 && tid == 0) offs[N_NODES] = N_EDGES;
}

// x[v] = (1+eps)*h[v] + sum_{u in in-nbrs(v)} h[u]; wave per node, lane = feature
__global__ void aggregate_kernel(const float* __restrict__ h, const int* __restrict__ offs,
                                 const int* __restrict__ csr, const float* __restrict__ epsp,
                                 float* __restrict__ x) {
  int node = blockIdx.x * 4 + (threadIdx.x >> 6);
  if (node >= N_NODES) return;
  int lane = threadIdx.x & 63;
  int beg = offs[node], end = offs[node + 1];
  float acc = (1.0f + epsp[0]) * h[(size_t)node * DDIM + lane];
  int e = beg;
  for (; e + 8 <= end; e += 8) {       // 8 gathers in flight (latency-bound)
    int u[8];
    #pragma unroll
    for (int q = 0; q < 8; ++q) u[q] = csr[e + q];
    float a[8];
    #pragma unroll
    for (int q = 0; q < 8; ++q) a[q] = h[(size_t)u[q] * DDIM + lane];
    acc += ((a[0] + a[1]) + (a[2] + a[3])) + ((a[4] + a[5]) + (a[6] + a[7]));
  }
  for (; e < end; ++e) acc += h[(size_t)csr[e] * DDIM + lane];
  x[(size_t)node * DDIM + lane] = acc;
}

// pack W1,W2,W3 into MFMA B-fragment order, SPLIT bf16: hi=bf16(w), lo=bf16(w-hi).
// frag f = (L*2 + kc)*4 + t; lane l holds W[kc*32 + (l>>4)*8 + e][t*16 + (l&15)]
// wbuf[f*64+lane] = hi frags; wbuf[1536 + f*64+lane] = lo frags
__global__ void pack_weights_kernel(const float* __restrict__ W1, const float* __restrict__ W2,
                                    const float* __restrict__ W3, bf16x8* __restrict__ wbuf) {
  int i = blockIdx.x * 256 + threadIdx.x;
  if (i >= 24 * 64) return;
  int lane = i & 63;
  int frag = i >> 6;
  int t = frag & 3;
  int kc = (frag >> 2) & 1;
  int L = frag >> 3;
  const float* W = (L == 0) ? W1 : ((L == 1) ? W2 : W3);
  int l15 = lane & 15, lg = lane >> 4;
  bf16x8 fh, fl;
  #pragma unroll
  for (int e = 0; e < 8; ++e) {
    int k = kc * 32 + lg * 8 + e;
    float w = W[k * 64 + t * 16 + l15];
    __bf16 hi = (__bf16)w;
    fh[e] = hi;
    fl[e] = (__bf16)(w - (float)hi);
  }
  wbuf[i] = fh;
  wbuf[24 * 64 + i] = fl;
}

__device__ __forceinline__ void split8(const f32x4& v0, const f32x4& v1,
                                       bf16x8& hi, bf16x8& lo) {
  #pragma unroll
  for (int e = 0; e < 4; ++e) {
    __bf16 h0 = (__bf16)v0[e];
    __bf16 h1 = (__bf16)v1[e];
    hi[e] = h0;     lo[e] = (__bf16)(v0[e] - (float)h0);
    hi[4 + e] = h1; lo[4 + e] = (__bf16)(v1[e] - (float)h1);
  }
}

#define MFMA(A, B, C) __builtin_amdgcn_mfma_f32_16x16x32_bf16((A), (B), (C), 0, 0, 0)

// one output col-tile T of layer L: 3-term split-bf16 product, all names literal.
#define DOT(L, T, BIASV, ACC)                                        \
  {                                                                  \
    bf16x8 bh0 = wbuf[(((L) * 2 + 0) * 4 + (T)) * 64 + lane];        \
    bf16x8 bh1 = wbuf[(((L) * 2 + 1) * 4 + (T)) * 64 + lane];        \
    bf16x8 bl0 = wbuf[1536 + (((L) * 2 + 0) * 4 + (T)) * 64 + lane]; \
    bf16x8 bl1 = wbuf[1536 + (((L) * 2 + 1) * 4 + (T)) * 64 + lane]; \
    f32x4 a_ = {(BIASV), (BIASV), (BIASV), (BIASV)};                 \
    a_ = MFMA(A0h, bh0, a_);                                         \
    a_ = MFMA(A1h, bh1, a_);                                         \
    a_ = MFMA(A0l, bh0, a_);                                         \
    a_ = MFMA(A1l, bh1, a_);                                         \
    a_ = MFMA(A0h, bl0, a_);                                         \
    a_ = MFMA(A1h, bl1, a_);                                         \
    ACC = a_;                                                        \
  }

#define DOLAYER(L)                   \
  DOT(L, 0, bias##L[0], acc0)        \
  DOT(L, 1, bias##L[1], acc1)        \
  DOT(L, 2, bias##L[2], acc2)        \
  DOT(L, 3, bias##L[3], acc3)

// relu(acc) -> per-wave LDS scratch (pitch 68), literal element indices
#define STORE_T(T, A)                                         \
  sc[(4 * lg + 0) * 68 + (T) * 16 + l15] = fmaxf(A[0], 0.f);  \
  sc[(4 * lg + 1) * 68 + (T) * 16 + l15] = fmaxf(A[1], 0.f);  \
  sc[(4 * lg + 2) * 68 + (T) * 16 + l15] = fmaxf(A[2], 0.f);  \
  sc[(4 * lg + 3) * 68 + (T) * 16 + l15] = fmaxf(A[3], 0.f);

#define TRANSITION                                            \
  {                                                           \
    STORE_T(0, acc0)                                          \
    STORE_T(1, acc1)                                          \
    STORE_T(2, acc2)                                          \
    STORE_T(3, acc3)                                          \
    const float* rp = sc + l15 * 68 + lg * 8;                 \
    f32x4 r0 = *(const f32x4*)(rp);                           \
    f32x4 r1 = *(const f32x4*)(rp + 4);                       \
    f32x4 r2 = *(const f32x4*)(rp + 32);                      \
    f32x4 r3 = *(const f32x4*)(rp + 36);                      \
    split8(r0, r1, A0h, A0l);                                 \
    split8(r2, r3, A1h, A1l);                                 \
  }

// epilogue col-tile: relu, guarded store, per-wave BN partials -> LDS (NO atomics)
#define EPI_T(T, A)                                                       \
  {                                                                       \
    float v0 = fmaxf(A[0], 0.f), v1 = fmaxf(A[1], 0.f);                   \
    float v2 = fmaxf(A[2], 0.f), v3 = fmaxf(A[3], 0.f);                   \
    if (active) {                                                         \
      xout[(size_t)(rows0 + 4 * lg + 0) * DDIM + (T) * 16 + l15] = v0;    \
      xout[(size_t)(rows0 + 4 * lg + 1) * DDIM + (T) * 16 + l15] = v1;    \
      xout[(size_t)(rows0 + 4 * lg + 2) * DDIM + (T) * 16 + l15] = v2;    \
      xout[(size_t)(rows0 + 4 * lg + 3) * DDIM + (T) * 16 + l15] = v3;    \
    }                                                                     \
    float vs = (v0 + v1) + (v2 + v3);                                     \
    float vq = ((v0 * v0 + v1 * v1) + (v2 * v2 + v3 * v3));               \
    vs += __shfl_xor(vs, 16); vs += __shfl_xor(vs, 32);                   \
    vq += __shfl_xor(vq, 16); vq += __shfl_xor(vq, 32);                   \
    if (lane < 16) {                                                      \
      bnred[0][wave][(T) * 16 + l15] = vs;                                \
      bnred[1][wave][(T) * 16 + l15] = vq;                                \
    }                                                                     \
  }

// MFMA MLP: wave per 16-row tile; split-bf16 in, f32 accum; block-local BN partials
__global__ __launch_bounds__(256) void mlp_kernel(
    const float* __restrict__ xin, float* __restrict__ xout,
    const bf16x8* __restrict__ wbuf,
    const float* __restrict__ b1, const float* __restrict__ b2, const float* __restrict__ b3,
    float* __restrict__ partial) {
  __shared__ float scratch[4][16 * 68];
  __shared__ float bnred[2][4][64];
  const int tid = threadIdx.x;
  const int lane = tid & 63, wave = tid >> 6;
  const int l15 = lane & 15, lg = lane >> 4;
  const int rows0 = blockIdx.x * 64 + wave * 16;
  const bool active = rows0 < N_NODES;
  float* sc = scratch[wave];

  f32x4 acc0 = {0.f, 0.f, 0.f, 0.f}, acc1 = acc0, acc2 = acc0, acc3 = acc0;

  if (active) {
    float bias0[4], bias1[4], bias2[4];
    #pragma unroll
    for (int t = 0; t < 4; ++t) {
      bias0[t] = b1[t * 16 + l15];
      bias1[t] = b2[t * 16 + l15];
      bias2[t] = b3[t * 16 + l15];
    }

    // layer-1 A fragments straight from global (rows L2/L3-resident)
    const float* xrow = xin + (size_t)(rows0 + l15) * DDIM;
    bf16x8 A0h, A0l, A1h, A1l;
    {
      f32x4 v0 = *(const f32x4*)(xrow + lg * 8);
      f32x4 v1 = *(const f32x4*)(xrow + lg * 8 + 4);
      f32x4 v2 = *(const f32x4*)(xrow + 32 + lg * 8);
      f32x4 v3 = *(const f32x4*)(xrow + 32 + lg * 8 + 4);
      split8(v0, v1, A0h, A0l);
      split8(v2, v3, A1h, A1l);
    }

    DOLAYER(0)
    TRANSITION
    DOLAYER(1)
    TRANSITION
    DOLAYER(2)
  }

  EPI_T(0, acc0)
  EPI_T(1, acc1)
  EPI_T(2, acc2)
  EPI_T(3, acc3)

  __syncthreads();
  if (tid < 128) {                     // [0..63]=sum, [64..127]=sq
    int s = tid >> 6, c = tid & 63;
    partial[(size_t)blockIdx.x * 128 + tid] =
        (bnred[s][0][c] + bnred[s][1][c]) + (bnred[s][2][c] + bnred[s][3][c]);
  }
}

// single block, 128 threads: reduce NB partials, produce mean + rsqrt(var)
__global__ void bn_reduce_kernel(const float* __restrict__ partial,
                                 float* __restrict__ stats) {
  int tid = threadIdx.x;               // 128
  float acc = 0.f;
  #pragma unroll 4
  for (int b = 0; b < NB; ++b) acc += partial[(size_t)b * 128 + tid];
  __shared__ float s[128];
  s[tid] = acc;
  __syncthreads();
  if (tid < 64) {
    const float invN = 1.0f / N_NODES;
    float m = s[tid] * invN;
    float var = s[64 + tid] * invN - m * m;
    stats[tid] = m;
    stats[64 + tid] = 1.0f / sqrtf(var + 1e-5f);
  }
}

// BN-apply -> h, plus atomic-free graph pooling (block per graph; graph_ids sorted)
__global__ void norm_pool_kernel(const float* __restrict__ x, float* __restrict__ h,
                                 float* __restrict__ pooled, const int* __restrict__ goff,
                                 const float* __restrict__ stats, const float* __restrict__ gamma,
                                 const float* __restrict__ beta, int iter) {
  int g = blockIdx.x;
  int lane = threadIdx.x & 63;
  int wave = threadIdx.x >> 6;
  float mean = stats[lane];
  float inv = stats[64 + lane];
  float gm = gamma[lane] * inv;
  float bt = beta[lane] - mean * gm;   // h = gm*v + bt
  int rbeg = goff[g], rend = goff[g + 1];
  float acc = 0.f;
  for (int r = rbeg + wave; r < rend; r += 4) {
    float v = fmaf(x[(size_t)r * DDIM + lane], gm, bt);
    h[(size_t)r * DDIM + lane] = v;
    acc += v;
  }
  __shared__ float red[4][64];
  red[wave][lane] = acc;
  __syncthreads();
  if (wave == 0) {
    pooled[(size_t)g * (ITERS * DDIM) + iter * DDIM + lane] =
        red[0][lane] + red[1][lane] + red[2][lane] + red[3][lane];
  }
}

__global__ void classifier_kernel(const float* __restrict__ pooled, const float* __restrict__ Wc,
                                  const float* __restrict__ bc, float* __restrict__ out) {
  int g = blockIdx.x;
  int c = threadIdx.x;
  if (c >= N_CLASSES) return;
  float acc = bc[c];
  #pragma unroll 4
  for (int k = 0; k < ITERS * DDIM; ++k)
    acc = fmaf(pooled[(size_t)g * (ITERS * DDIM) + k], Wc[k * N_CLASSES + c], acc);
  out[(size_t)g * N_CLASSES + c] = acc;
}

extern "C" void kernel_launch(void* const* d_in, const int* in_sizes, int n_in,
                              void* d_out, int out_size, void* d_ws, size_t ws_size,
                              hipStream_t stream) {
  const int*   pkt   = (const int*)d_in[0];
  const int*   src   = (const int*)d_in[1];
  const int*   dst   = (const int*)d_in[2];
  const int*   gids  = (const int*)d_in[3];
  const float* emb   = (const float*)d_in[4];
  const float* eps   = (const float*)d_in[5];
  const float* W1    = (const float*)d_in[6];
  const float* b1    = (const float*)d_in[7];
  const float* W2    = (const float*)d_in[8];
  const float* b2    = (const float*)d_in[9];
  const float* W3    = (const float*)d_in[10];
  const float* b3    = (const float*)d_in[11];
  const float* gamma = (const float*)d_in[12];
  const float* beta  = (const float*)d_in[13];
  const float* Wc    = (const float*)d_in[14];
  const float* bc    = (const float*)d_in[15];
  float* out = (float*)d_out;

  char* p = (char*)d_ws;
  auto alloc = [&](size_t bytes) {
    char* r = p;
    p += (bytes + 255) & ~(size_t)255;
    return r;
  };
  float*    h       = (float*)alloc((size_t)N_NODES * DDIM * 4);
  float*    x       = (float*)alloc((size_t)N_NODES * DDIM * 4);
  unsigned* ebuf    = (unsigned*)alloc((size_t)N_EDGES * 4);
  int*      csr     = (int*)alloc((size_t)N_EDGES * 4);
  int*      offs    = (int*)alloc((size_t)(N_NODES + 1) * 4);
  int*      boffs   = (int*)alloc((size_t)(NB + 1) * 4);
  int*      bcursor = (int*)alloc((size_t)NB * 4);
  int*      goff    = (int*)alloc((size_t)(N_GRAPHS + 1) * 4);
  float*    pooled  = (float*)alloc((size_t)N_GRAPHS * ITERS * DDIM * 4);
  float*    stats   = (float*)alloc(128 * 4);
  bf16x8*   wbuf    = (bf16x8*)alloc((size_t)48 * 64 * 16);   // hi + lo fragments
  float*    partial = (float*)alloc((size_t)NB * 128 * 4);
  // contiguous zero region: bhist | gcnt
  size_t zbytes = (size_t)NB * 4 + (size_t)N_GRAPHS * 4;
  char*  zbase  = alloc(zbytes);
  int*   bhist  = (int*)zbase;
  int*   gcnt   = bhist + NB;

  hipMemsetAsync(zbase, 0, zbytes, stream);

  embed_kernel<<<(N_NODES * 16 + 255) / 256, 256, 0, stream>>>(pkt, (const float4*)emb,
                                                               (float4*)h);
  bucket_hist_kernel<<<256, 256, 0, stream>>>(dst, bhist);
  hist_kernel<<<(N_NODES + 255) / 256, 256, 0, stream>>>(gids, gcnt, N_NODES);
  scan_kernel<<<1, 1024, 0, stream>>>(bhist, boffs, bcursor, NB);
  scan_kernel<<<1, 1024, 0, stream>>>(gcnt, goff, nullptr, N_GRAPHS);
  partition_kernel<<<NPB, 256, 0, stream>>>(src, dst, bcursor, ebuf);
  local_scatter_kernel<<<NB, 256, 0, stream>>>(ebuf, boffs, offs, csr);
  pack_weights_kernel<<<6, 256, 0, stream>>>(W1, W2, W3, wbuf);

  for (int it = 0; it < ITERS; ++it) {
    aggregate_kernel<<<(N_NODES + 3) / 4, 256, 0, stream>>>(h, offs, csr, eps, x);
    mlp_kernel<<<NB, 256, 0, stream>>>(x, x, wbuf, b1, b2, b3, partial);
    bn_reduce_kernel<<<1, 128, 0, stream>>>(partial, stats);
    norm_pool_kernel<<<N_GRAPHS, 256, 0, stream>>>(x, h, pooled, goff, stats, gamma, beta, it);
  }
  classifier_kernel<<<N_GRAPHS, 64, 0, stream>>>(pooled, Wc, bc, out);
}

// Round 8
// 391.291 us; speedup vs baseline: 2.1034x; 1.7000x over previous
//
#include <hip/hip_runtime.h>

#define N_NODES   50000
#define N_EDGES   1600000
#define DDIM      64
#define N_GRAPHS  512
#define N_CLASSES 53
#define ITERS     3
#define NB        782            // ceil(N_NODES/64) buckets of 64 dst nodes
#define PPITCH    800            // partial row pitch (>= NB)
#define NPB       128            // partition blocks
#define CHUNK     ((N_EDGES + NPB - 1) / NPB)

typedef __bf16 bf16x8 __attribute__((ext_vector_type(8)));
typedef float  f32x4  __attribute__((ext_vector_type(4)));

// h[node][d] = emb[pkt[node]][d], float4-vectorized
__global__ void embed_kernel(const int* __restrict__ pkt, const float4* __restrict__ emb,
                             float4* __restrict__ h) {
  int idx = blockIdx.x * 256 + threadIdx.x;
  if (idx >= N_NODES * 16) return;
  int node = idx >> 4;
  h[idx] = emb[(size_t)pkt[node] * 16 + (idx & 15)];
}

// edge-count per 64-node dst bucket, LDS-staged
__global__ void bucket_hist_kernel(const int* __restrict__ dst, int* __restrict__ bhist) {
  __shared__ int lh[NB];
  for (int i = threadIdx.x; i < NB; i += 256) lh[i] = 0;
  __syncthreads();
  int stride = gridDim.x * 256;
  for (int e = blockIdx.x * 256 + threadIdx.x; e < N_EDGES; e += stride)
    atomicAdd(&lh[dst[e] >> 6], 1);
  __syncthreads();
  for (int i = threadIdx.x; i < NB; i += 256)
    if (lh[i]) atomicAdd(&bhist[i], lh[i]);
}

__global__ void hist_kernel(const int* __restrict__ idx, int* __restrict__ counts, int n) {
  int i = blockIdx.x * 256 + threadIdx.x;
  if (i < n) atomicAdd(&counts[idx[i]], 1);
}

// single-block exclusive scan; offs[n] = total; optional cursor copy
__global__ void scan_kernel(const int* __restrict__ counts, int* __restrict__ offs,
                            int* __restrict__ cursor, int n) {
  __shared__ int wsum[16];
  __shared__ int carry;
  int tid = threadIdx.x;               // 1024 threads
  if (tid == 0) carry = 0;
  __syncthreads();
  for (int base = 0; base < n; base += 1024) {
    int i = base + tid;
    int v = (i < n) ? counts[i] : 0;
    int x = v;
    #pragma unroll
    for (int off = 1; off < 64; off <<= 1) {
      int y = __shfl_up(x, off);
      if ((tid & 63) >= off) x += y;
    }
    int w = tid >> 6;
    if ((tid & 63) == 63) wsum[w] = x;
    __syncthreads();
    int woff = 0;
    for (int k = 0; k < w; ++k) woff += wsum[k];
    int incl = x + woff + carry;
    if (i < n) {
      offs[i] = incl - v;
      if (cursor) cursor[i] = incl - v;
    }
    __syncthreads();
    if (tid == 1023) carry = incl;
    __syncthreads();
  }
  if (tid == 0) offs[n] = carry;
}

// bucket-partition edges: ebuf[pos] = src(16b) | (dst&63)<<16, grouped by dst>>6
__global__ void partition_kernel(const int* __restrict__ src, const int* __restrict__ dst,
                                 int* __restrict__ bcursor, unsigned* __restrict__ ebuf) {
  __shared__ int lh[NB];
  __shared__ int lbase[NB];
  for (int i = threadIdx.x; i < NB; i += 256) lh[i] = 0;
  __syncthreads();
  int e0 = blockIdx.x * CHUNK;
  int e1 = min(e0 + CHUNK, N_EDGES);
  for (int e = e0 + (int)threadIdx.x; e < e1; e += 256)
    atomicAdd(&lh[dst[e] >> 6], 1);
  __syncthreads();
  for (int i = threadIdx.x; i < NB; i += 256) {
    int c = lh[i];
    lbase[i] = c ? atomicAdd(&bcursor[i], c) : 0;
    lh[i] = 0;                         // reuse as running cursor
  }
  __syncthreads();
  for (int e = e0 + (int)threadIdx.x; e < e1; e += 256) {
    int d = dst[e];
    int b = d >> 6;
    int pos = lbase[b] + atomicAdd(&lh[b], 1);
    ebuf[pos] = (unsigned)src[e] | ((unsigned)(d & 63) << 16);
  }
}

// block per bucket: per-node offsets (in-block 64-scan) + CSR scatter locally
__global__ __launch_bounds__(256) void local_scatter_kernel(
    const unsigned* __restrict__ ebuf, const int* __restrict__ boffs,
    int* __restrict__ offs, int* __restrict__ csr) {
  __shared__ int cnt[64];
  __shared__ int base[64];
  const int b = blockIdx.x;
  const int tid = threadIdx.x;
  if (tid < 64) cnt[tid] = 0;
  __syncthreads();
  const int ebeg = boffs[b], eend = boffs[b + 1];
  for (int e = ebeg + tid; e < eend; e += 256)
    atomicAdd(&cnt[(ebuf[e] >> 16) & 63u], 1);
  __syncthreads();
  if (tid < 64) {                      // wave 0: exclusive scan of 64 counts
    int v = cnt[tid];
    int x = v;
    #pragma unroll
    for (int off = 1; off < 64; off <<= 1) {
      int y = __shfl_up(x, off);
      if (tid >= off) x += y;
    }
    int excl = ebeg + x - v;
    base[tid] = excl;
    int node = b * 64 + tid;
    if (node < N_NODES) offs[node] = excl;
    cnt[tid] = 0;                      // reuse as running cursor
  }
  __syncthreads();
  for (int e = ebeg + tid; e < eend; e += 256) {
    unsigned p = ebuf[e];
    int j = (p >> 16) & 63u;
    int pos = base[j] + atomicAdd(&cnt[j], 1);
    csr[pos] = (int)(p & 0xFFFFu);
  }
  if (b == NB - 1 && tid == 0) offs[N_NODES] = N_EDGES;
}

// x[v] = (1+eps)*h[v] + sum_{u in in-nbrs(v)} h[u]; wave per node, lane = feature
__global__ void aggregate_kernel(const float* __restrict__ h, const int* __restrict__ offs,
                                 const int* __restrict__ csr, const float* __restrict__ epsp,
                                 float* __restrict__ x) {
  int node = blockIdx.x * 4 + (threadIdx.x >> 6);
  if (node >= N_NODES) return;
  int lane = threadIdx.x & 63;
  int beg = offs[node], end = offs[node + 1];
  float acc = (1.0f + epsp[0]) * h[(size_t)node * DDIM + lane];
  int e = beg;
  for (; e + 8 <= end; e += 8) {       // 8 gathers in flight (latency-bound)
    int u[8];
    #pragma unroll
    for (int q = 0; q < 8; ++q) u[q] = csr[e + q];
    float a[8];
    #pragma unroll
    for (int q = 0; q < 8; ++q) a[q] = h[(size_t)u[q] * DDIM + lane];
    acc += ((a[0] + a[1]) + (a[2] + a[3])) + ((a[4] + a[5]) + (a[6] + a[7]));
  }
  for (; e < end; ++e) acc += h[(size_t)csr[e] * DDIM + lane];
  x[(size_t)node * DDIM + lane] = acc;
}

// pack W1,W2,W3 into MFMA B-fragment order, SPLIT bf16: hi=bf16(w), lo=bf16(w-hi).
// frag f = (L*2 + kc)*4 + t; lane l holds W[kc*32 + (l>>4)*8 + e][t*16 + (l&15)]
// wbuf[f*64+lane] = hi frags; wbuf[1536 + f*64+lane] = lo frags
__global__ void pack_weights_kernel(const float* __restrict__ W1, const float* __restrict__ W2,
                                    const float* __restrict__ W3, bf16x8* __restrict__ wbuf) {
  int i = blockIdx.x * 256 + threadIdx.x;
  if (i >= 24 * 64) return;
  int lane = i & 63;
  int frag = i >> 6;
  int t = frag & 3;
  int kc = (frag >> 2) & 1;
  int L = frag >> 3;
  const float* W = (L == 0) ? W1 : ((L == 1) ? W2 : W3);
  int l15 = lane & 15, lg = lane >> 4;
  bf16x8 fh, fl;
  #pragma unroll
  for (int e = 0; e < 8; ++e) {
    int k = kc * 32 + lg * 8 + e;
    float w = W[k * 64 + t * 16 + l15];
    __bf16 hi = (__bf16)w;
    fh[e] = hi;
    fl[e] = (__bf16)(w - (float)hi);
  }
  wbuf[i] = fh;
  wbuf[24 * 64 + i] = fl;
}

__device__ __forceinline__ void split8(const f32x4& v0, const f32x4& v1,
                                       bf16x8& hi, bf16x8& lo) {
  #pragma unroll
  for (int e = 0; e < 4; ++e) {
    __bf16 h0 = (__bf16)v0[e];
    __bf16 h1 = (__bf16)v1[e];
    hi[e] = h0;     lo[e] = (__bf16)(v0[e] - (float)h0);
    hi[4 + e] = h1; lo[4 + e] = (__bf16)(v1[e] - (float)h1);
  }
}

#define MFMA(A, B, C) __builtin_amdgcn_mfma_f32_16x16x32_bf16((A), (B), (C), 0, 0, 0)

// one output col-tile T of layer L: 3-term split-bf16 product, all names literal.
#define DOT(L, T, BIASV, ACC)                                        \
  {                                                                  \
    bf16x8 bh0 = wbuf[(((L) * 2 + 0) * 4 + (T)) * 64 + lane];        \
    bf16x8 bh1 = wbuf[(((L) * 2 + 1) * 4 + (T)) * 64 + lane];        \
    bf16x8 bl0 = wbuf[1536 + (((L) * 2 + 0) * 4 + (T)) * 64 + lane]; \
    bf16x8 bl1 = wbuf[1536 + (((L) * 2 + 1) * 4 + (T)) * 64 + lane]; \
    f32x4 a_ = {(BIASV), (BIASV), (BIASV), (BIASV)};                 \
    a_ = MFMA(A0h, bh0, a_);                                         \
    a_ = MFMA(A1h, bh1, a_);                                         \
    a_ = MFMA(A0l, bh0, a_);                                         \
    a_ = MFMA(A1l, bh1, a_);                                         \
    a_ = MFMA(A0h, bl0, a_);                                         \
    a_ = MFMA(A1h, bl1, a_);                                         \
    ACC = a_;                                                        \
  }

#define DOLAYER(L)                   \
  DOT(L, 0, bias##L[0], acc0)        \
  DOT(L, 1, bias##L[1], acc1)        \
  DOT(L, 2, bias##L[2], acc2)        \
  DOT(L, 3, bias##L[3], acc3)

// relu(acc) -> per-wave LDS scratch (pitch 68), literal element indices
#define STORE_T(T, A)                                         \
  sc[(4 * lg + 0) * 68 + (T) * 16 + l15] = fmaxf(A[0], 0.f);  \
  sc[(4 * lg + 1) * 68 + (T) * 16 + l15] = fmaxf(A[1], 0.f);  \
  sc[(4 * lg + 2) * 68 + (T) * 16 + l15] = fmaxf(A[2], 0.f);  \
  sc[(4 * lg + 3) * 68 + (T) * 16 + l15] = fmaxf(A[3], 0.f);

#define TRANSITION                                            \
  {                                                           \
    STORE_T(0, acc0)                                          \
    STORE_T(1, acc1)                                          \
    STORE_T(2, acc2)                                          \
    STORE_T(3, acc3)                                          \
    const float* rp = sc + l15 * 68 + lg * 8;                 \
    f32x4 r0 = *(const f32x4*)(rp);                           \
    f32x4 r1 = *(const f32x4*)(rp + 4);                       \
    f32x4 r2 = *(const f32x4*)(rp + 32);                      \
    f32x4 r3 = *(const f32x4*)(rp + 36);                      \
    split8(r0, r1, A0h, A0l);                                 \
    split8(r2, r3, A1h, A1l);                                 \
  }

// epilogue col-tile: relu, guarded store, per-wave BN partials -> LDS (NO atomics)
#define EPI_T(T, A)                                                       \
  {                                                                       \
    float v0 = fmaxf(A[0], 0.f), v1 = fmaxf(A[1], 0.f);                   \
    float v2 = fmaxf(A[2], 0.f), v3 = fmaxf(A[3], 0.f);                   \
    if (active) {                                                         \
      xout[(size_t)(rows0 + 4 * lg + 0) * DDIM + (T) * 16 + l15] = v0;    \
      xout[(size_t)(rows0 + 4 * lg + 1) * DDIM + (T) * 16 + l15] = v1;    \
      xout[(size_t)(rows0 + 4 * lg + 2) * DDIM + (T) * 16 + l15] = v2;    \
      xout[(size_t)(rows0 + 4 * lg + 3) * DDIM + (T) * 16 + l15] = v3;    \
    }                                                                     \
    float vs = (v0 + v1) + (v2 + v3);                                     \
    float vq = ((v0 * v0 + v1 * v1) + (v2 * v2 + v3 * v3));               \
    vs += __shfl_xor(vs, 16); vs += __shfl_xor(vs, 32);                   \
    vq += __shfl_xor(vq, 16); vq += __shfl_xor(vq, 32);                   \
    if (lane < 16) {                                                      \
      bnred[0][wave][(T) * 16 + l15] = vs;                                \
      bnred[1][wave][(T) * 16 + l15] = vq;                                \
    }                                                                     \
  }

// MFMA MLP: wave per 16-row tile; split-bf16 in, f32 accum; block-local BN partials
// partial layout: partial[col * PPITCH + block]  (col 0..63 = sum, 64..127 = sq)
__global__ __launch_bounds__(256) void mlp_kernel(
    const float* __restrict__ xin, float* __restrict__ xout,
    const bf16x8* __restrict__ wbuf,
    const float* __restrict__ b1, const float* __restrict__ b2, const float* __restrict__ b3,
    float* __restrict__ partial) {
  __shared__ float scratch[4][16 * 68];
  __shared__ float bnred[2][4][64];
  const int tid = threadIdx.x;
  const int lane = tid & 63, wave = tid >> 6;
  const int l15 = lane & 15, lg = lane >> 4;
  const int rows0 = blockIdx.x * 64 + wave * 16;
  const bool active = rows0 < N_NODES;
  float* sc = scratch[wave];

  f32x4 acc0 = {0.f, 0.f, 0.f, 0.f}, acc1 = acc0, acc2 = acc0, acc3 = acc0;

  if (active) {
    float bias0[4], bias1[4], bias2[4];
    #pragma unroll
    for (int t = 0; t < 4; ++t) {
      bias0[t] = b1[t * 16 + l15];
      bias1[t] = b2[t * 16 + l15];
      bias2[t] = b3[t * 16 + l15];
    }

    // layer-1 A fragments straight from global (rows L2/L3-resident)
    const float* xrow = xin + (size_t)(rows0 + l15) * DDIM;
    bf16x8 A0h, A0l, A1h, A1l;
    {
      f32x4 v0 = *(const f32x4*)(xrow + lg * 8);
      f32x4 v1 = *(const f32x4*)(xrow + lg * 8 + 4);
      f32x4 v2 = *(const f32x4*)(xrow + 32 + lg * 8);
      f32x4 v3 = *(const f32x4*)(xrow + 32 + lg * 8 + 4);
      split8(v0, v1, A0h, A0l);
      split8(v2, v3, A1h, A1l);
    }

    DOLAYER(0)
    TRANSITION
    DOLAYER(1)
    TRANSITION
    DOLAYER(2)
  }

  EPI_T(0, acc0)
  EPI_T(1, acc1)
  EPI_T(2, acc2)
  EPI_T(3, acc3)

  __syncthreads();
  if (tid < 128) {                     // row (=col of stats) 0..127, transposed write
    int s = tid >> 6, c = tid & 63;
    partial[(size_t)tid * PPITCH + blockIdx.x] =
        (bnred[s][0][c] + bnred[s][1][c]) + (bnred[s][2][c] + bnred[s][3][c]);
  }
}

// wave per stats-row: sum NB contiguous partials -> colsum[row]
__global__ void bn_stats_kernel(const float* __restrict__ partial,
                                float* __restrict__ colsum) {
  int row = blockIdx.x * 4 + (threadIdx.x >> 6);   // 32 blocks x 4 waves = 128 rows
  int lane = threadIdx.x & 63;
  const float* rp = partial + (size_t)row * PPITCH;
  float acc = 0.f;
  for (int i = lane; i < NB; i += 64) acc += rp[i];
  #pragma unroll
  for (int off = 32; off > 0; off >>= 1) acc += __shfl_down(acc, off);
  if (lane == 0) colsum[row] = acc;
}

__global__ void bn_finalize_kernel(const float* __restrict__ colsum,
                                   float* __restrict__ stats) {
  int lane = threadIdx.x;              // 64 threads
  const float invN = 1.0f / N_NODES;
  float m = colsum[lane] * invN;
  float var = colsum[64 + lane] * invN - m * m;
  stats[lane] = m;
  stats[64 + lane] = 1.0f / sqrtf(var + 1e-5f);
}

// BN-apply -> h, plus atomic-free graph pooling (block per graph; graph_ids sorted)
__global__ void norm_pool_kernel(const float* __restrict__ x, float* __restrict__ h,
                                 float* __restrict__ pooled, const int* __restrict__ goff,
                                 const float* __restrict__ stats, const float* __restrict__ gamma,
                                 const float* __restrict__ beta, int iter) {
  int g = blockIdx.x;
  int lane = threadIdx.x & 63;
  int wave = threadIdx.x >> 6;
  float mean = stats[lane];
  float inv = stats[64 + lane];
  float gm = gamma[lane] * inv;
  float bt = beta[lane] - mean * gm;   // h = gm*v + bt
  int rbeg = goff[g], rend = goff[g + 1];
  float acc = 0.f;
  for (int r = rbeg + wave; r < rend; r += 4) {
    float v = fmaf(x[(size_t)r * DDIM + lane], gm, bt);
    h[(size_t)r * DDIM + lane] = v;
    acc += v;
  }
  __shared__ float red[4][64];
  red[wave][lane] = acc;
  __syncthreads();
  if (wave == 0) {
    pooled[(size_t)g * (ITERS * DDIM) + iter * DDIM + lane] =
        red[0][lane] + red[1][lane] + red[2][lane] + red[3][lane];
  }
}

__global__ void classifier_kernel(const float* __restrict__ pooled, const float* __restrict__ Wc,
                                  const float* __restrict__ bc, float* __restrict__ out) {
  int g = blockIdx.x;
  int c = threadIdx.x;
  if (c >= N_CLASSES) return;
  float acc = bc[c];
  #pragma unroll 4
  for (int k = 0; k < ITERS * DDIM; ++k)
    acc = fmaf(pooled[(size_t)g * (ITERS * DDIM) + k], Wc[k * N_CLASSES + c], acc);
  out[(size_t)g * N_CLASSES + c] = acc;
}

extern "C" void kernel_launch(void* const* d_in, const int* in_sizes, int n_in,
                              void* d_out, int out_size, void* d_ws, size_t ws_size,
                              hipStream_t stream) {
  const int*   pkt   = (const int*)d_in[0];
  const int*   src   = (const int*)d_in[1];
  const int*   dst   = (const int*)d_in[2];
  const int*   gids  = (const int*)d_in[3];
  const float* emb   = (const float*)d_in[4];
  const float* eps   = (const float*)d_in[5];
  const float* W1    = (const float*)d_in[6];
  const float* b1    = (const float*)d_in[7];
  const float* W2    = (const float*)d_in[8];
  const float* b2    = (const float*)d_in[9];
  const float* W3    = (const float*)d_in[10];
  const float* b3    = (const float*)d_in[11];
  const float* gamma = (const float*)d_in[12];
  const float* beta  = (const float*)d_in[13];
  const float* Wc    = (const float*)d_in[14];
  const float* bc    = (const float*)d_in[15];
  float* out = (float*)d_out;

  char* p = (char*)d_ws;
  auto alloc = [&](size_t bytes) {
    char* r = p;
    p += (bytes + 255) & ~(size_t)255;
    return r;
  };
  float*    h       = (float*)alloc((size_t)N_NODES * DDIM * 4);
  float*    x       = (float*)alloc((size_t)N_NODES * DDIM * 4);
  unsigned* ebuf    = (unsigned*)alloc((size_t)N_EDGES * 4);
  int*      csr     = (int*)alloc((size_t)N_EDGES * 4);
  int*      offs    = (int*)alloc((size_t)(N_NODES + 1) * 4);
  int*      boffs   = (int*)alloc((size_t)(NB + 1) * 4);
  int*      bcursor = (int*)alloc((size_t)NB * 4);
  int*      goff    = (int*)alloc((size_t)(N_GRAPHS + 1) * 4);
  float*    pooled  = (float*)alloc((size_t)N_GRAPHS * ITERS * DDIM * 4);
  float*    stats   = (float*)alloc(128 * 4);
  float*    colsum  = (float*)alloc(128 * 4);
  bf16x8*   wbuf    = (bf16x8*)alloc((size_t)48 * 64 * 16);   // hi + lo fragments
  float*    partial = (float*)alloc((size_t)128 * PPITCH * 4);
  // contiguous zero region: bhist | gcnt
  size_t zbytes = (size_t)NB * 4 + (size_t)N_GRAPHS * 4;
  char*  zbase  = alloc(zbytes);
  int*   bhist  = (int*)zbase;
  int*   gcnt   = bhist + NB;

  hipMemsetAsync(zbase, 0, zbytes, stream);

  embed_kernel<<<(N_NODES * 16 + 255) / 256, 256, 0, stream>>>(pkt, (const float4*)emb,
                                                               (float4*)h);
  bucket_hist_kernel<<<256, 256, 0, stream>>>(dst, bhist);
  hist_kernel<<<(N_NODES + 255) / 256, 256, 0, stream>>>(gids, gcnt, N_NODES);
  scan_kernel<<<1, 1024, 0, stream>>>(bhist, boffs, bcursor, NB);
  scan_kernel<<<1, 1024, 0, stream>>>(gcnt, goff, nullptr, N_GRAPHS);
  partition_kernel<<<NPB, 256, 0, stream>>>(src, dst, bcursor, ebuf);
  local_scatter_kernel<<<NB, 256, 0, stream>>>(ebuf, boffs, offs, csr);
  pack_weights_kernel<<<6, 256, 0, stream>>>(W1, W2, W3, wbuf);

  for (int it = 0; it < ITERS; ++it) {
    aggregate_kernel<<<(N_NODES + 3) / 4, 256, 0, stream>>>(h, offs, csr, eps, x);
    mlp_kernel<<<NB, 256, 0, stream>>>(x, x, wbuf, b1, b2, b3, partial);
    bn_stats_kernel<<<32, 256, 0, stream>>>(partial, colsum);
    bn_finalize_kernel<<<1, 64, 0, stream>>>(colsum, stats);
    norm_pool_kernel<<<N_GRAPHS, 256, 0, stream>>>(x, h, pooled, goff, stats, gamma, beta, it);
  }
  classifier_kernel<<<N_GRAPHS, 64, 0, stream>>>(pooled, Wc, bc, out);
}

// Round 9
// 350.785 us; speedup vs baseline: 2.3463x; 1.1155x over previous
//
#include <hip/hip_runtime.h>

#define N_NODES   50000
#define N_EDGES   1600000
#define DDIM      64
#define N_GRAPHS  512
#define N_CLASSES 53
#define ITERS     3
#define NB        782            // ceil(N_NODES/64) buckets of 64 dst nodes
#define PPITCH    800            // partial row pitch (>= NB)
#define NPB       512            // partition blocks (parallelism for scattered writes)
#define CHUNK     ((N_EDGES + NPB - 1) / NPB)

typedef __bf16 bf16x8 __attribute__((ext_vector_type(8)));
typedef __bf16 bf16x4 __attribute__((ext_vector_type(4)));
typedef float  f32x4  __attribute__((ext_vector_type(4)));

// hb[node][d] = bf16(emb[pkt[node]][d]) — bf16 node features (halves gather traffic)
__global__ void embed_kernel(const int* __restrict__ pkt, const float4* __restrict__ emb,
                             bf16x4* __restrict__ hb4) {
  int idx = blockIdx.x * 256 + threadIdx.x;           // over N_NODES*16 float4s
  if (idx >= N_NODES * 16) return;
  int node = idx >> 4;
  float4 v = emb[(size_t)pkt[node] * 16 + (idx & 15)];
  bf16x4 o;
  o[0] = (__bf16)v.x; o[1] = (__bf16)v.y; o[2] = (__bf16)v.z; o[3] = (__bf16)v.w;
  hb4[idx] = o;
}

// edge-count per 64-node dst bucket, LDS-staged
__global__ void bucket_hist_kernel(const int* __restrict__ dst, int* __restrict__ bhist) {
  __shared__ int lh[NB];
  for (int i = threadIdx.x; i < NB; i += 256) lh[i] = 0;
  __syncthreads();
  int stride = gridDim.x * 256;
  for (int e = blockIdx.x * 256 + threadIdx.x; e < N_EDGES; e += stride)
    atomicAdd(&lh[dst[e] >> 6], 1);
  __syncthreads();
  for (int i = threadIdx.x; i < NB; i += 256)
    if (lh[i]) atomicAdd(&bhist[i], lh[i]);
}

__global__ void hist_kernel(const int* __restrict__ idx, int* __restrict__ counts, int n) {
  int i = blockIdx.x * 256 + threadIdx.x;
  if (i < n) atomicAdd(&counts[idx[i]], 1);
}

// single-block exclusive scan; offs[n] = total; optional cursor copy
__global__ void scan_kernel(const int* __restrict__ counts, int* __restrict__ offs,
                            int* __restrict__ cursor, int n) {
  __shared__ int wsum[16];
  __shared__ int carry;
  int tid = threadIdx.x;               // 1024 threads
  if (tid == 0) carry = 0;
  __syncthreads();
  for (int base = 0; base < n; base += 1024) {
    int i = base + tid;
    int v = (i < n) ? counts[i] : 0;
    int x = v;
    #pragma unroll
    for (int off = 1; off < 64; off <<= 1) {
      int y = __shfl_up(x, off);
      if ((tid & 63) >= off) x += y;
    }
    int w = tid >> 6;
    if ((tid & 63) == 63) wsum[w] = x;
    __syncthreads();
    int woff = 0;
    for (int k = 0; k < w; ++k) woff += wsum[k];
    int incl = x + woff + carry;
    if (i < n) {
      offs[i] = incl - v;
      if (cursor) cursor[i] = incl - v;
    }
    __syncthreads();
    if (tid == 1023) carry = incl;
    __syncthreads();
  }
  if (tid == 0) offs[n] = carry;
}

// bucket-partition edges: ebuf[pos] = src(16b) | (dst&63)<<16, grouped by dst>>6
__global__ void partition_kernel(const int* __restrict__ src, const int* __restrict__ dst,
                                 int* __restrict__ bcursor, unsigned* __restrict__ ebuf) {
  __shared__ int lh[NB];
  __shared__ int lbase[NB];
  for (int i = threadIdx.x; i < NB; i += 256) lh[i] = 0;
  __syncthreads();
  int e0 = blockIdx.x * CHUNK;
  int e1 = min(e0 + CHUNK, N_EDGES);
  for (int e = e0 + (int)threadIdx.x; e < e1; e += 256)
    atomicAdd(&lh[dst[e] >> 6], 1);
  __syncthreads();
  for (int i = threadIdx.x; i < NB; i += 256) {
    int c = lh[i];
    lbase[i] = c ? atomicAdd(&bcursor[i], c) : 0;
    lh[i] = 0;                         // reuse as running cursor
  }
  __syncthreads();
  for (int e = e0 + (int)threadIdx.x; e < e1; e += 256) {
    int d = dst[e];
    int b = d >> 6;
    int pos = lbase[b] + atomicAdd(&lh[b], 1);
    ebuf[pos] = (unsigned)src[e] | ((unsigned)(d & 63) << 16);
  }
}

// block per bucket: per-node offsets (in-block 64-scan) + CSR scatter locally
__global__ __launch_bounds__(256) void local_scatter_kernel(
    const unsigned* __restrict__ ebuf, const int* __restrict__ boffs,
    int* __restrict__ offs, int* __restrict__ csr) {
  __shared__ int cnt[64];
  __shared__ int base[64];
  const int b = blockIdx.x;
  const int tid = threadIdx.x;
  if (tid < 64) cnt[tid] = 0;
  __syncthreads();
  const int ebeg = boffs[b], eend = boffs[b + 1];
  for (int e = ebeg + tid; e < eend; e += 256)
    atomicAdd(&cnt[(ebuf[e] >> 16) & 63u], 1);
  __syncthreads();
  if (tid < 64) {                      // wave 0: exclusive scan of 64 counts
    int v = cnt[tid];
    int x = v;
    #pragma unroll
    for (int off = 1; off < 64; off <<= 1) {
      int y = __shfl_up(x, off);
      if (tid >= off) x += y;
    }
    int excl = ebeg + x - v;
    base[tid] = excl;
    int node = b * 64 + tid;
    if (node < N_NODES) offs[node] = excl;
    cnt[tid] = 0;                      // reuse as running cursor
  }
  __syncthreads();
  for (int e = ebeg + tid; e < eend; e += 256) {
    unsigned p = ebuf[e];
    int j = (p >> 16) & 63u;
    int pos = base[j] + atomicAdd(&cnt[j], 1);
    csr[pos] = (int)(p & 0xFFFFu);
  }
  if (b == NB - 1 && tid == 0) offs[N_NODES] = N_EDGES;
}

// x[v] = (1+eps)*hb[v] + sum_{u in in-nbrs(v)} hb[u]; wave per node, lane = feature
// bf16 gathers (128B/row) halve L3 traffic; accumulate f32
__global__ void aggregate_kernel(const __bf16* __restrict__ hb, const int* __restrict__ offs,
                                 const int* __restrict__ csr, const float* __restrict__ epsp,
                                 float* __restrict__ x) {
  int node = blockIdx.x * 4 + (threadIdx.x >> 6);
  if (node >= N_NODES) return;
  int lane = threadIdx.x & 63;
  int beg = offs[node], end = offs[node + 1];
  float acc = (1.0f + epsp[0]) * (float)hb[(size_t)node * DDIM + lane];
  int e = beg;
  for (; e + 8 <= end; e += 8) {       // 8 gathers in flight (latency/L3-BW-bound)
    int u[8];
    #pragma unroll
    for (int q = 0; q < 8; ++q) u[q] = csr[e + q];
    float a[8];
    #pragma unroll
    for (int q = 0; q < 8; ++q) a[q] = (float)hb[(size_t)u[q] * DDIM + lane];
    acc += ((a[0] + a[1]) + (a[2] + a[3])) + ((a[4] + a[5]) + (a[6] + a[7]));
  }
  for (; e < end; ++e) acc += (float)hb[(size_t)csr[e] * DDIM + lane];
  x[(size_t)node * DDIM + lane] = acc;
}

// pack W1,W2,W3 into MFMA B-fragment order, SPLIT bf16: hi=bf16(w), lo=bf16(w-hi).
// frag f = (L*2 + kc)*4 + t; lane l holds W[kc*32 + (l>>4)*8 + e][t*16 + (l&15)]
// wbuf[f*64+lane] = hi frags; wbuf[1536 + f*64+lane] = lo frags
__global__ void pack_weights_kernel(const float* __restrict__ W1, const float* __restrict__ W2,
                                    const float* __restrict__ W3, bf16x8* __restrict__ wbuf) {
  int i = blockIdx.x * 256 + threadIdx.x;
  if (i >= 24 * 64) return;
  int lane = i & 63;
  int frag = i >> 6;
  int t = frag & 3;
  int kc = (frag >> 2) & 1;
  int L = frag >> 3;
  const float* W = (L == 0) ? W1 : ((L == 1) ? W2 : W3);
  int l15 = lane & 15, lg = lane >> 4;
  bf16x8 fh, fl;
  #pragma unroll
  for (int e = 0; e < 8; ++e) {
    int k = kc * 32 + lg * 8 + e;
    float w = W[k * 64 + t * 16 + l15];
    __bf16 hi = (__bf16)w;
    fh[e] = hi;
    fl[e] = (__bf16)(w - (float)hi);
  }
  wbuf[i] = fh;
  wbuf[24 * 64 + i] = fl;
}

__device__ __forceinline__ void split8(const f32x4& v0, const f32x4& v1,
                                       bf16x8& hi, bf16x8& lo) {
  #pragma unroll
  for (int e = 0; e < 4; ++e) {
    __bf16 h0 = (__bf16)v0[e];
    __bf16 h1 = (__bf16)v1[e];
    hi[e] = h0;     lo[e] = (__bf16)(v0[e] - (float)h0);
    hi[4 + e] = h1; lo[4 + e] = (__bf16)(v1[e] - (float)h1);
  }
}

#define MFMA(A, B, C) __builtin_amdgcn_mfma_f32_16x16x32_bf16((A), (B), (C), 0, 0, 0)

// one output col-tile T of layer L: 3-term split-bf16 product, all names literal.
#define DOT(L, T, BIASV, ACC)                                        \
  {                                                                  \
    bf16x8 bh0 = wbuf[(((L) * 2 + 0) * 4 + (T)) * 64 + lane];        \
    bf16x8 bh1 = wbuf[(((L) * 2 + 1) * 4 + (T)) * 64 + lane];        \
    bf16x8 bl0 = wbuf[1536 + (((L) * 2 + 0) * 4 + (T)) * 64 + lane]; \
    bf16x8 bl1 = wbuf[1536 + (((L) * 2 + 1) * 4 + (T)) * 64 + lane]; \
    f32x4 a_ = {(BIASV), (BIASV), (BIASV), (BIASV)};                 \
    a_ = MFMA(A0h, bh0, a_);                                         \
    a_ = MFMA(A1h, bh1, a_);                                         \
    a_ = MFMA(A0l, bh0, a_);                                         \
    a_ = MFMA(A1l, bh1, a_);                                         \
    a_ = MFMA(A0h, bl0, a_);                                         \
    a_ = MFMA(A1h, bl1, a_);                                         \
    ACC = a_;                                                        \
  }

#define DOLAYER(L)                   \
  DOT(L, 0, bias##L[0], acc0)        \
  DOT(L, 1, bias##L[1], acc1)        \
  DOT(L, 2, bias##L[2], acc2)        \
  DOT(L, 3, bias##L[3], acc3)

// relu(acc) -> per-wave LDS scratch (pitch 68), literal element indices
#define STORE_T(T, A)                                         \
  sc[(4 * lg + 0) * 68 + (T) * 16 + l15] = fmaxf(A[0], 0.f);  \
  sc[(4 * lg + 1) * 68 + (T) * 16 + l15] = fmaxf(A[1], 0.f);  \
  sc[(4 * lg + 2) * 68 + (T) * 16 + l15] = fmaxf(A[2], 0.f);  \
  sc[(4 * lg + 3) * 68 + (T) * 16 + l15] = fmaxf(A[3], 0.f);

#define TRANSITION                                            \
  {                                                           \
    STORE_T(0, acc0)                                          \
    STORE_T(1, acc1)                                          \
    STORE_T(2, acc2)                                          \
    STORE_T(3, acc3)                                          \
    const float* rp = sc + l15 * 68 + lg * 8;                 \
    f32x4 r0 = *(const f32x4*)(rp);                           \
    f32x4 r1 = *(const f32x4*)(rp + 4);                       \
    f32x4 r2 = *(const f32x4*)(rp + 32);                      \
    f32x4 r3 = *(const f32x4*)(rp + 36);                      \
    split8(r0, r1, A0h, A0l);                                 \
    split8(r2, r3, A1h, A1l);                                 \
  }

// epilogue col-tile: relu, guarded store, per-wave BN partials -> LDS (NO atomics)
#define EPI_T(T, A)                                                       \
  {                                                                       \
    float v0 = fmaxf(A[0], 0.f), v1 = fmaxf(A[1], 0.f);                   \
    float v2 = fmaxf(A[2], 0.f), v3 = fmaxf(A[3], 0.f);                   \
    if (active) {                                                         \
      xout[(size_t)(rows0 + 4 * lg + 0) * DDIM + (T) * 16 + l15] = v0;    \
      xout[(size_t)(rows0 + 4 * lg + 1) * DDIM + (T) * 16 + l15] = v1;    \
      xout[(size_t)(rows0 + 4 * lg + 2) * DDIM + (T) * 16 + l15] = v2;    \
      xout[(size_t)(rows0 + 4 * lg + 3) * DDIM + (T) * 16 + l15] = v3;    \
    }                                                                     \
    float vs = (v0 + v1) + (v2 + v3);                                     \
    float vq = ((v0 * v0 + v1 * v1) + (v2 * v2 + v3 * v3));               \
    vs += __shfl_xor(vs, 16); vs += __shfl_xor(vs, 32);                   \
    vq += __shfl_xor(vq, 16); vq += __shfl_xor(vq, 32);                   \
    if (lane < 16) {                                                      \
      bnred[0][wave][(T) * 16 + l15] = vs;                                \
      bnred[1][wave][(T) * 16 + l15] = vq;                                \
    }                                                                     \
  }

// MFMA MLP: wave per 16-row tile; split-bf16 in, f32 accum; block-local BN partials
// partial layout: partial[col * PPITCH + block]  (col 0..63 = sum, 64..127 = sq)
__global__ __launch_bounds__(256) void mlp_kernel(
    const float* __restrict__ xin, float* __restrict__ xout,
    const bf16x8* __restrict__ wbuf,
    const float* __restrict__ b1, const float* __restrict__ b2, const float* __restrict__ b3,
    float* __restrict__ partial) {
  __shared__ float scratch[4][16 * 68];
  __shared__ float bnred[2][4][64];
  const int tid = threadIdx.x;
  const int lane = tid & 63, wave = tid >> 6;
  const int l15 = lane & 15, lg = lane >> 4;
  const int rows0 = blockIdx.x * 64 + wave * 16;
  const bool active = rows0 < N_NODES;
  float* sc = scratch[wave];

  f32x4 acc0 = {0.f, 0.f, 0.f, 0.f}, acc1 = acc0, acc2 = acc0, acc3 = acc0;

  if (active) {
    float bias0[4], bias1[4], bias2[4];
    #pragma unroll
    for (int t = 0; t < 4; ++t) {
      bias0[t] = b1[t * 16 + l15];
      bias1[t] = b2[t * 16 + l15];
      bias2[t] = b3[t * 16 + l15];
    }

    // layer-1 A fragments straight from global (rows L2/L3-resident)
    const float* xrow = xin + (size_t)(rows0 + l15) * DDIM;
    bf16x8 A0h, A0l, A1h, A1l;
    {
      f32x4 v0 = *(const f32x4*)(xrow + lg * 8);
      f32x4 v1 = *(const f32x4*)(xrow + lg * 8 + 4);
      f32x4 v2 = *(const f32x4*)(xrow + 32 + lg * 8);
      f32x4 v3 = *(const f32x4*)(xrow + 32 + lg * 8 + 4);
      split8(v0, v1, A0h, A0l);
      split8(v2, v3, A1h, A1l);
    }

    DOLAYER(0)
    TRANSITION
    DOLAYER(1)
    TRANSITION
    DOLAYER(2)
  }

  EPI_T(0, acc0)
  EPI_T(1, acc1)
  EPI_T(2, acc2)
  EPI_T(3, acc3)

  __syncthreads();
  if (tid < 128) {                     // row (=col of stats) 0..127, transposed write
    int s = tid >> 6, c = tid & 63;
    partial[(size_t)tid * PPITCH + blockIdx.x] =
        (bnred[s][0][c] + bnred[s][1][c]) + (bnred[s][2][c] + bnred[s][3][c]);
  }
}

// wave per stats-row: sum NB contiguous partials -> colsum[row]
__global__ void bn_stats_kernel(const float* __restrict__ partial,
                                float* __restrict__ colsum) {
  int row = blockIdx.x * 4 + (threadIdx.x >> 6);   // 32 blocks x 4 waves = 128 rows
  int lane = threadIdx.x & 63;
  const float* rp = partial + (size_t)row * PPITCH;
  float acc = 0.f;
  for (int i = lane; i < NB; i += 64) acc += rp[i];
  #pragma unroll
  for (int off = 32; off > 0; off >>= 1) acc += __shfl_down(acc, off);
  if (lane == 0) colsum[row] = acc;
}

__global__ void bn_finalize_kernel(const float* __restrict__ colsum,
                                   float* __restrict__ stats) {
  int lane = threadIdx.x;              // 64 threads
  const float invN = 1.0f / N_NODES;
  float m = colsum[lane] * invN;
  float var = colsum[64 + lane] * invN - m * m;
  stats[lane] = m;
  stats[64 + lane] = 1.0f / sqrtf(var + 1e-5f);
}

// BN-apply -> hb (bf16), plus atomic-free graph pooling (block per graph; sorted ids)
__global__ void norm_pool_kernel(const float* __restrict__ x, __bf16* __restrict__ hb,
                                 float* __restrict__ pooled, const int* __restrict__ goff,
                                 const float* __restrict__ stats, const float* __restrict__ gamma,
                                 const float* __restrict__ beta, int iter) {
  int g = blockIdx.x;
  int lane = threadIdx.x & 63;
  int wave = threadIdx.x >> 6;
  float mean = stats[lane];
  float inv = stats[64 + lane];
  float gm = gamma[lane] * inv;
  float bt = beta[lane] - mean * gm;   // h = gm*v + bt
  int rbeg = goff[g], rend = goff[g + 1];
  float acc = 0.f;
  for (int r = rbeg + wave; r < rend; r += 4) {
    float v = fmaf(x[(size_t)r * DDIM + lane], gm, bt);
    hb[(size_t)r * DDIM + lane] = (__bf16)v;
    acc += v;                          // pooled keeps full f32 precision
  }
  __shared__ float red[4][64];
  red[wave][lane] = acc;
  __syncthreads();
  if (wave == 0) {
    pooled[(size_t)g * (ITERS * DDIM) + iter * DDIM + lane] =
        red[0][lane] + red[1][lane] + red[2][lane] + red[3][lane];
  }
}

__global__ void classifier_kernel(const float* __restrict__ pooled, const float* __restrict__ Wc,
                                  const float* __restrict__ bc, float* __restrict__ out) {
  int g = blockIdx.x;
  int c = threadIdx.x;
  if (c >= N_CLASSES) return;
  float acc = bc[c];
  #pragma unroll 4
  for (int k = 0; k < ITERS * DDIM; ++k)
    acc = fmaf(pooled[(size_t)g * (ITERS * DDIM) + k], Wc[k * N_CLASSES + c], acc);
  out[(size_t)g * N_CLASSES + c] = acc;
}

extern "C" void kernel_launch(void* const* d_in, const int* in_sizes, int n_in,
                              void* d_out, int out_size, void* d_ws, size_t ws_size,
                              hipStream_t stream) {
  const int*   pkt   = (const int*)d_in[0];
  const int*   src   = (const int*)d_in[1];
  const int*   dst   = (const int*)d_in[2];
  const int*   gids  = (const int*)d_in[3];
  const float* emb   = (const float*)d_in[4];
  const float* eps   = (const float*)d_in[5];
  const float* W1    = (const float*)d_in[6];
  const float* b1    = (const float*)d_in[7];
  const float* W2    = (const float*)d_in[8];
  const float* b2    = (const float*)d_in[9];
  const float* W3    = (const float*)d_in[10];
  const float* b3    = (const float*)d_in[11];
  const float* gamma = (const float*)d_in[12];
  const float* beta  = (const float*)d_in[13];
  const float* Wc    = (const float*)d_in[14];
  const float* bc    = (const float*)d_in[15];
  float* out = (float*)d_out;

  char* p = (char*)d_ws;
  auto alloc = [&](size_t bytes) {
    char* r = p;
    p += (bytes + 255) & ~(size_t)255;
    return r;
  };
  __bf16*   hb      = (__bf16*)alloc((size_t)N_NODES * DDIM * 2);
  float*    x       = (float*)alloc((size_t)N_NODES * DDIM * 4);
  unsigned* ebuf    = (unsigned*)alloc((size_t)N_EDGES * 4);
  int*      csr     = (int*)alloc((size_t)N_EDGES * 4);
  int*      offs    = (int*)alloc((size_t)(N_NODES + 1) * 4);
  int*      boffs   = (int*)alloc((size_t)(NB + 1) * 4);
  int*      bcursor = (int*)alloc((size_t)NB * 4);
  int*      goff    = (int*)alloc((size_t)(N_GRAPHS + 1) * 4);
  float*    pooled  = (float*)alloc((size_t)N_GRAPHS * ITERS * DDIM * 4);
  float*    stats   = (float*)alloc(128 * 4);
  float*    colsum  = (float*)alloc(128 * 4);
  bf16x8*   wbuf    = (bf16x8*)alloc((size_t)48 * 64 * 16);   // hi + lo fragments
  float*    partial = (float*)alloc((size_t)128 * PPITCH * 4);
  // contiguous zero region: bhist | gcnt
  size_t zbytes = (size_t)NB * 4 + (size_t)N_GRAPHS * 4;
  char*  zbase  = alloc(zbytes);
  int*   bhist  = (int*)zbase;
  int*   gcnt   = bhist + NB;

  hipMemsetAsync(zbase, 0, zbytes, stream);

  embed_kernel<<<(N_NODES * 16 + 255) / 256, 256, 0, stream>>>(pkt, (const float4*)emb,
                                                               (bf16x4*)hb);
  bucket_hist_kernel<<<512, 256, 0, stream>>>(dst, bhist);
  hist_kernel<<<(N_NODES + 255) / 256, 256, 0, stream>>>(gids, gcnt, N_NODES);
  scan_kernel<<<1, 1024, 0, stream>>>(bhist, boffs, bcursor, NB);
  scan_kernel<<<1, 1024, 0, stream>>>(gcnt, goff, nullptr, N_GRAPHS);
  partition_kernel<<<NPB, 256, 0, stream>>>(src, dst, bcursor, ebuf);
  local_scatter_kernel<<<NB, 256, 0, stream>>>(ebuf, boffs, offs, csr);
  pack_weights_kernel<<<6, 256, 0, stream>>>(W1, W2, W3, wbuf);

  for (int it = 0; it < ITERS; ++it) {
    aggregate_kernel<<<(N_NODES + 3) / 4, 256, 0, stream>>>(hb, offs, csr, eps, x);
    mlp_kernel<<<NB, 256, 0, stream>>>(x, x, wbuf, b1, b2, b3, partial);
    bn_stats_kernel<<<32, 256, 0, stream>>>(partial, colsum);
    bn_finalize_kernel<<<1, 64, 0, stream>>>(colsum, stats);
    norm_pool_kernel<<<N_GRAPHS, 256, 0, stream>>>(x, hb, pooled, goff, stats, gamma, beta, it);
  }
  classifier_kernel<<<N_GRAPHS, 64, 0, stream>>>(pooled, Wc, bc, out);
}

// Round 10
// 312.686 us; speedup vs baseline: 2.6322x; 1.1218x over previous
//
#include <hip/hip_runtime.h>

#define N_NODES   50000
#define N_EDGES   1600000
#define DDIM      64
#define N_GRAPHS  512
#define N_CLASSES 53
#define ITERS     3
#define NB        782            // ceil(N_NODES/64) buckets of 64 dst nodes
#define PPITCH    800            // partial row pitch (>= NB)
#define NPB       512            // partition blocks (parallelism for scattered writes)
#define CHUNK     ((N_EDGES + NPB - 1) / NPB)

typedef __bf16 bf16x8 __attribute__((ext_vector_type(8)));
typedef __bf16 bf16x4 __attribute__((ext_vector_type(4)));
typedef float  f32x4  __attribute__((ext_vector_type(4)));

// hb[node][d] = bf16(emb[pkt[node]][d]) — bf16 node features (halves gather traffic)
__global__ void embed_kernel(const int* __restrict__ pkt, const float4* __restrict__ emb,
                             bf16x4* __restrict__ hb4) {
  int idx = blockIdx.x * 256 + threadIdx.x;           // over N_NODES*16 float4s
  if (idx >= N_NODES * 16) return;
  int node = idx >> 4;
  float4 v = emb[(size_t)pkt[node] * 16 + (idx & 15)];
  bf16x4 o;
  o[0] = (__bf16)v.x; o[1] = (__bf16)v.y; o[2] = (__bf16)v.z; o[3] = (__bf16)v.w;
  hb4[idx] = o;
}

// edge-count per 64-node dst bucket, LDS-staged
__global__ void bucket_hist_kernel(const int* __restrict__ dst, int* __restrict__ bhist) {
  __shared__ int lh[NB];
  for (int i = threadIdx.x; i < NB; i += 256) lh[i] = 0;
  __syncthreads();
  int stride = gridDim.x * 256;
  for (int e = blockIdx.x * 256 + threadIdx.x; e < N_EDGES; e += stride)
    atomicAdd(&lh[dst[e] >> 6], 1);
  __syncthreads();
  for (int i = threadIdx.x; i < NB; i += 256)
    if (lh[i]) atomicAdd(&bhist[i], lh[i]);
}

__global__ void hist_kernel(const int* __restrict__ idx, int* __restrict__ counts, int n) {
  int i = blockIdx.x * 256 + threadIdx.x;
  if (i < n) atomicAdd(&counts[idx[i]], 1);
}

// single-block exclusive scan; offs[n] = total; optional cursor copy
__global__ void scan_kernel(const int* __restrict__ counts, int* __restrict__ offs,
                            int* __restrict__ cursor, int n) {
  __shared__ int wsum[16];
  __shared__ int carry;
  int tid = threadIdx.x;               // 1024 threads
  if (tid == 0) carry = 0;
  __syncthreads();
  for (int base = 0; base < n; base += 1024) {
    int i = base + tid;
    int v = (i < n) ? counts[i] : 0;
    int x = v;
    #pragma unroll
    for (int off = 1; off < 64; off <<= 1) {
      int y = __shfl_up(x, off);
      if ((tid & 63) >= off) x += y;
    }
    int w = tid >> 6;
    if ((tid & 63) == 63) wsum[w] = x;
    __syncthreads();
    int woff = 0;
    for (int k = 0; k < w; ++k) woff += wsum[k];
    int incl = x + woff + carry;
    if (i < n) {
      offs[i] = incl - v;
      if (cursor) cursor[i] = incl - v;
    }
    __syncthreads();
    if (tid == 1023) carry = incl;
    __syncthreads();
  }
  if (tid == 0) offs[n] = carry;
}

// bucket-partition edges: ebuf[pos] = src(16b) | (dst&63)<<16, grouped by dst>>6
__global__ void partition_kernel(const int* __restrict__ src, const int* __restrict__ dst,
                                 int* __restrict__ bcursor, unsigned* __restrict__ ebuf) {
  __shared__ int lh[NB];
  __shared__ int lbase[NB];
  for (int i = threadIdx.x; i < NB; i += 256) lh[i] = 0;
  __syncthreads();
  int e0 = blockIdx.x * CHUNK;
  int e1 = min(e0 + CHUNK, N_EDGES);
  for (int e = e0 + (int)threadIdx.x; e < e1; e += 256)
    atomicAdd(&lh[dst[e] >> 6], 1);
  __syncthreads();
  for (int i = threadIdx.x; i < NB; i += 256) {
    int c = lh[i];
    lbase[i] = c ? atomicAdd(&bcursor[i], c) : 0;
    lh[i] = 0;                         // reuse as running cursor
  }
  __syncthreads();
  for (int e = e0 + (int)threadIdx.x; e < e1; e += 256) {
    int d = dst[e];
    int b = d >> 6;
    int pos = lbase[b] + atomicAdd(&lh[b], 1);
    ebuf[pos] = (unsigned)src[e] | ((unsigned)(d & 63) << 16);
  }
}

// block per bucket: per-node offsets (in-block 64-scan) + CSR scatter locally
__global__ __launch_bounds__(256) void local_scatter_kernel(
    const unsigned* __restrict__ ebuf, const int* __restrict__ boffs,
    int* __restrict__ offs, int* __restrict__ csr) {
  __shared__ int cnt[64];
  __shared__ int base[64];
  const int b = blockIdx.x;
  const int tid = threadIdx.x;
  if (tid < 64) cnt[tid] = 0;
  __syncthreads();
  const int ebeg = boffs[b], eend = boffs[b + 1];
  for (int e = ebeg + tid; e < eend; e += 256)
    atomicAdd(&cnt[(ebuf[e] >> 16) & 63u], 1);
  __syncthreads();
  if (tid < 64) {                      // wave 0: exclusive scan of 64 counts
    int v = cnt[tid];
    int x = v;
    #pragma unroll
    for (int off = 1; off < 64; off <<= 1) {
      int y = __shfl_up(x, off);
      if (tid >= off) x += y;
    }
    int excl = ebeg + x - v;
    base[tid] = excl;
    int node = b * 64 + tid;
    if (node < N_NODES) offs[node] = excl;
    cnt[tid] = 0;                      // reuse as running cursor
  }
  __syncthreads();
  for (int e = ebeg + tid; e < eend; e += 256) {
    unsigned p = ebuf[e];
    int j = (p >> 16) & 63u;
    int pos = base[j] + atomicAdd(&cnt[j], 1);
    csr[pos] = (int)(p & 0xFFFFu);
  }
  if (b == NB - 1 && tid == 0) offs[N_NODES] = N_EDGES;
}

// x[v] = (1+eps)*hb[v] + sum_{u} hb[u]; wave per node, PAIRED-DWORD gathers:
// lanes 0-31 = edge e0's row (32 dwords), lanes 32-63 = edge e1 -> 256B/instr
__global__ void aggregate_kernel(const __bf16* __restrict__ hb, const int* __restrict__ offs,
                                 const int* __restrict__ csr, const float* __restrict__ epsp,
                                 float* __restrict__ x) {
  int node = blockIdx.x * 4 + (threadIdx.x >> 6);
  if (node >= N_NODES) return;
  const int lane = threadIdx.x & 63;
  const int fp = lane & 31;            // feature-pair index (features 2fp, 2fp+1)
  const int half = lane >> 5;
  const unsigned* __restrict__ hrow = (const unsigned*)hb;   // [node][32] dwords
  const int beg = offs[node], end = offs[node + 1];

  float acc0 = 0.f, acc1 = 0.f;
  {
    unsigned w = hrow[(size_t)node * 32 + fp];
    float ep = 1.0f + epsp[0];
    if (half == 0) {                   // self term counted once
      acc0 = ep * __uint_as_float(w << 16);
      acc1 = ep * __uint_as_float(w & 0xffff0000u);
    }
  }
  int e = beg;
  for (; e + 16 <= end; e += 16) {     // 8 dword-loads in flight = 16 edges
    int pk = (lane < 16) ? csr[e + lane] : 0;
    #pragma unroll
    for (int q = 0; q < 8; ++q) {
      int u = __shfl(pk, 2 * q + half);
      unsigned w = hrow[(size_t)u * 32 + fp];
      acc0 += __uint_as_float(w << 16);
      acc1 += __uint_as_float(w & 0xffff0000u);
    }
  }
  int rem = end - e;
  if (rem > 0) {
    int pk = (lane < rem) ? csr[e + lane] : 0;
    int np = rem >> 1;
    for (int q = 0; q < np; ++q) {
      int u = __shfl(pk, 2 * q + half);
      unsigned w = hrow[(size_t)u * 32 + fp];
      acc0 += __uint_as_float(w << 16);
      acc1 += __uint_as_float(w & 0xffff0000u);
    }
    if (rem & 1) {
      int u = __shfl(pk, rem - 1);
      if (half == 0) {
        unsigned w = hrow[(size_t)u * 32 + fp];
        acc0 += __uint_as_float(w << 16);
        acc1 += __uint_as_float(w & 0xffff0000u);
      }
    }
  }
  acc0 += __shfl_xor(acc0, 32);        // combine the two edge-halves
  acc1 += __shfl_xor(acc1, 32);
  if (half == 0) {
    float2 o = {acc0, acc1};
    *(float2*)(x + (size_t)node * DDIM + fp * 2) = o;
  }
}

// pack W1,W2,W3 into MFMA B-fragment order, SPLIT bf16: hi=bf16(w), lo=bf16(w-hi).
__global__ void pack_weights_kernel(const float* __restrict__ W1, const float* __restrict__ W2,
                                    const float* __restrict__ W3, bf16x8* __restrict__ wbuf) {
  int i = blockIdx.x * 256 + threadIdx.x;
  if (i >= 24 * 64) return;
  int lane = i & 63;
  int frag = i >> 6;
  int t = frag & 3;
  int kc = (frag >> 2) & 1;
  int L = frag >> 3;
  const float* W = (L == 0) ? W1 : ((L == 1) ? W2 : W3);
  int l15 = lane & 15, lg = lane >> 4;
  bf16x8 fh, fl;
  #pragma unroll
  for (int e = 0; e < 8; ++e) {
    int k = kc * 32 + lg * 8 + e;
    float w = W[k * 64 + t * 16 + l15];
    __bf16 hi = (__bf16)w;
    fh[e] = hi;
    fl[e] = (__bf16)(w - (float)hi);
  }
  wbuf[i] = fh;
  wbuf[24 * 64 + i] = fl;
}

__device__ __forceinline__ void split8(const f32x4& v0, const f32x4& v1,
                                       bf16x8& hi, bf16x8& lo) {
  #pragma unroll
  for (int e = 0; e < 4; ++e) {
    __bf16 h0 = (__bf16)v0[e];
    __bf16 h1 = (__bf16)v1[e];
    hi[e] = h0;     lo[e] = (__bf16)(v0[e] - (float)h0);
    hi[4 + e] = h1; lo[4 + e] = (__bf16)(v1[e] - (float)h1);
  }
}

#define MFMA(A, B, C) __builtin_amdgcn_mfma_f32_16x16x32_bf16((A), (B), (C), 0, 0, 0)

// one output col-tile T of layer L: 3-term split-bf16 product, all names literal.
#define DOT(L, T, BIASV, ACC)                                        \
  {                                                                  \
    bf16x8 bh0 = wbuf[(((L) * 2 + 0) * 4 + (T)) * 64 + lane];        \
    bf16x8 bh1 = wbuf[(((L) * 2 + 1) * 4 + (T)) * 64 + lane];        \
    bf16x8 bl0 = wbuf[1536 + (((L) * 2 + 0) * 4 + (T)) * 64 + lane]; \
    bf16x8 bl1 = wbuf[1536 + (((L) * 2 + 1) * 4 + (T)) * 64 + lane]; \
    f32x4 a_ = {(BIASV), (BIASV), (BIASV), (BIASV)};                 \
    a_ = MFMA(A0h, bh0, a_);                                         \
    a_ = MFMA(A1h, bh1, a_);                                         \
    a_ = MFMA(A0l, bh0, a_);                                         \
    a_ = MFMA(A1l, bh1, a_);                                         \
    a_ = MFMA(A0h, bl0, a_);                                         \
    a_ = MFMA(A1h, bl1, a_);                                         \
    ACC = a_;                                                        \
  }

#define DOLAYER(L)                   \
  DOT(L, 0, bias##L[0], acc0)        \
  DOT(L, 1, bias##L[1], acc1)        \
  DOT(L, 2, bias##L[2], acc2)        \
  DOT(L, 3, bias##L[3], acc3)

// relu(acc) -> per-wave LDS scratch (pitch 68), literal element indices
#define STORE_T(T, A)                                         \
  sc[(4 * lg + 0) * 68 + (T) * 16 + l15] = fmaxf(A[0], 0.f);  \
  sc[(4 * lg + 1) * 68 + (T) * 16 + l15] = fmaxf(A[1], 0.f);  \
  sc[(4 * lg + 2) * 68 + (T) * 16 + l15] = fmaxf(A[2], 0.f);  \
  sc[(4 * lg + 3) * 68 + (T) * 16 + l15] = fmaxf(A[3], 0.f);

#define TRANSITION                                            \
  {                                                           \
    STORE_T(0, acc0)                                          \
    STORE_T(1, acc1)                                          \
    STORE_T(2, acc2)                                          \
    STORE_T(3, acc3)                                          \
    const float* rp = sc + l15 * 68 + lg * 8;                 \
    f32x4 r0 = *(const f32x4*)(rp);                           \
    f32x4 r1 = *(const f32x4*)(rp + 4);                       \
    f32x4 r2 = *(const f32x4*)(rp + 32);                      \
    f32x4 r3 = *(const f32x4*)(rp + 36);                      \
    split8(r0, r1, A0h, A0l);                                 \
    split8(r2, r3, A1h, A1l);                                 \
  }

// epilogue col-tile: relu, guarded store, per-wave BN partials -> LDS (NO atomics)
#define EPI_T(T, A)                                                       \
  {                                                                       \
    float v0 = fmaxf(A[0], 0.f), v1 = fmaxf(A[1], 0.f);                   \
    float v2 = fmaxf(A[2], 0.f), v3 = fmaxf(A[3], 0.f);                   \
    if (active) {                                                         \
      xout[(size_t)(rows0 + 4 * lg + 0) * DDIM + (T) * 16 + l15] = v0;    \
      xout[(size_t)(rows0 + 4 * lg + 1) * DDIM + (T) * 16 + l15] = v1;    \
      xout[(size_t)(rows0 + 4 * lg + 2) * DDIM + (T) * 16 + l15] = v2;    \
      xout[(size_t)(rows0 + 4 * lg + 3) * DDIM + (T) * 16 + l15] = v3;    \
    }                                                                     \
    float vs = (v0 + v1) + (v2 + v3);                                     \
    float vq = ((v0 * v0 + v1 * v1) + (v2 * v2 + v3 * v3));               \
    vs += __shfl_xor(vs, 16); vs += __shfl_xor(vs, 32);                   \
    vq += __shfl_xor(vq, 16); vq += __shfl_xor(vq, 32);                   \
    if (lane < 16) {                                                      \
      bnred[0][wave][(T) * 16 + l15] = vs;                                \
      bnred[1][wave][(T) * 16 + l15] = vq;                                \
    }                                                                     \
  }

// MFMA MLP: wave per 16-row tile; split-bf16 in, f32 accum; block-local BN partials
// partial layout: partial[col * PPITCH + block]  (col 0..63 = sum, 64..127 = sq)
__global__ __launch_bounds__(256) void mlp_kernel(
    const float* __restrict__ xin, float* __restrict__ xout,
    const bf16x8* __restrict__ wbuf,
    const float* __restrict__ b1, const float* __restrict__ b2, const float* __restrict__ b3,
    float* __restrict__ partial) {
  __shared__ float scratch[4][16 * 68];
  __shared__ float bnred[2][4][64];
  const int tid = threadIdx.x;
  const int lane = tid & 63, wave = tid >> 6;
  const int l15 = lane & 15, lg = lane >> 4;
  const int rows0 = blockIdx.x * 64 + wave * 16;
  const bool active = rows0 < N_NODES;
  float* sc = scratch[wave];

  f32x4 acc0 = {0.f, 0.f, 0.f, 0.f}, acc1 = acc0, acc2 = acc0, acc3 = acc0;

  if (active) {
    float bias0[4], bias1[4], bias2[4];
    #pragma unroll
    for (int t = 0; t < 4; ++t) {
      bias0[t] = b1[t * 16 + l15];
      bias1[t] = b2[t * 16 + l15];
      bias2[t] = b3[t * 16 + l15];
    }

    const float* xrow = xin + (size_t)(rows0 + l15) * DDIM;
    bf16x8 A0h, A0l, A1h, A1l;
    {
      f32x4 v0 = *(const f32x4*)(xrow + lg * 8);
      f32x4 v1 = *(const f32x4*)(xrow + lg * 8 + 4);
      f32x4 v2 = *(const f32x4*)(xrow + 32 + lg * 8);
      f32x4 v3 = *(const f32x4*)(xrow + 32 + lg * 8 + 4);
      split8(v0, v1, A0h, A0l);
      split8(v2, v3, A1h, A1l);
    }

    DOLAYER(0)
    TRANSITION
    DOLAYER(1)
    TRANSITION
    DOLAYER(2)
  }

  EPI_T(0, acc0)
  EPI_T(1, acc1)
  EPI_T(2, acc2)
  EPI_T(3, acc3)

  __syncthreads();
  if (tid < 128) {                     // transposed write: partial[col][block]
    int s = tid >> 6, c = tid & 63;
    partial[(size_t)tid * PPITCH + blockIdx.x] =
        (bnred[s][0][c] + bnred[s][1][c]) + (bnred[s][2][c] + bnred[s][3][c]);
  }
}

// wave per stats-row: sum NB contiguous partials -> colsum[row]
__global__ void bn_stats_kernel(const float* __restrict__ partial,
                                float* __restrict__ colsum) {
  int row = blockIdx.x * 4 + (threadIdx.x >> 6);   // 32 blocks x 4 waves = 128 rows
  int lane = threadIdx.x & 63;
  const float* rp = partial + (size_t)row * PPITCH;
  float acc = 0.f;
  for (int i = lane; i < NB; i += 64) acc += rp[i];
  #pragma unroll
  for (int off = 32; off > 0; off >>= 1) acc += __shfl_down(acc, off);
  if (lane == 0) colsum[row] = acc;
}

// BN-apply -> hb (bf16) + pooling; stats computed inline from colsum (no finalize pass)
__global__ void norm_pool_kernel(const float* __restrict__ x, __bf16* __restrict__ hb,
                                 float* __restrict__ pooled, const int* __restrict__ goff,
                                 const float* __restrict__ colsum, const float* __restrict__ gamma,
                                 const float* __restrict__ beta, int iter) {
  int g = blockIdx.x;
  int lane = threadIdx.x & 63;
  int wave = threadIdx.x >> 6;
  const float invN = 1.0f / N_NODES;
  float mean = colsum[lane] * invN;
  float var = colsum[64 + lane] * invN - mean * mean;
  float inv = 1.0f / sqrtf(var + 1e-5f);
  float gm = gamma[lane] * inv;
  float bt = beta[lane] - mean * gm;   // h = gm*v + bt
  int rbeg = goff[g], rend = goff[g + 1];
  float acc = 0.f;
  for (int r = rbeg + wave; r < rend; r += 4) {
    float v = fmaf(x[(size_t)r * DDIM + lane], gm, bt);
    hb[(size_t)r * DDIM + lane] = (__bf16)v;
    acc += v;                          // pooled keeps full f32 precision
  }
  __shared__ float red[4][64];
  red[wave][lane] = acc;
  __syncthreads();
  if (wave == 0) {
    pooled[(size_t)g * (ITERS * DDIM) + iter * DDIM + lane] =
        red[0][lane] + red[1][lane] + red[2][lane] + red[3][lane];
  }
}

__global__ void classifier_kernel(const float* __restrict__ pooled, const float* __restrict__ Wc,
                                  const float* __restrict__ bc, float* __restrict__ out) {
  int g = blockIdx.x;
  int c = threadIdx.x;
  if (c >= N_CLASSES) return;
  float acc = bc[c];
  #pragma unroll 4
  for (int k = 0; k < ITERS * DDIM; ++k)
    acc = fmaf(pooled[(size_t)g * (ITERS * DDIM) + k], Wc[k * N_CLASSES + c], acc);
  out[(size_t)g * N_CLASSES + c] = acc;
}

extern "C" void kernel_launch(void* const* d_in, const int* in_sizes, int n_in,
                              void* d_out, int out_size, void* d_ws, size_t ws_size,
                              hipStream_t stream) {
  const int*   pkt   = (const int*)d_in[0];
  const int*   src   = (const int*)d_in[1];
  const int*   dst   = (const int*)d_in[2];
  const int*   gids  = (const int*)d_in[3];
  const float* emb   = (const float*)d_in[4];
  const float* eps   = (const float*)d_in[5];
  const float* W1    = (const float*)d_in[6];
  const float* b1    = (const float*)d_in[7];
  const float* W2    = (const float*)d_in[8];
  const float* b2    = (const float*)d_in[9];
  const float* W3    = (const float*)d_in[10];
  const float* b3    = (const float*)d_in[11];
  const float* gamma = (const float*)d_in[12];
  const float* beta  = (const float*)d_in[13];
  const float* Wc    = (const float*)d_in[14];
  const float* bc    = (const float*)d_in[15];
  float* out = (float*)d_out;

  char* p = (char*)d_ws;
  auto alloc = [&](size_t bytes) {
    char* r = p;
    p += (bytes + 255) & ~(size_t)255;
    return r;
  };
  __bf16*   hb      = (__bf16*)alloc((size_t)N_NODES * DDIM * 2);
  float*    x       = (float*)alloc((size_t)N_NODES * DDIM * 4);
  unsigned* ebuf    = (unsigned*)alloc((size_t)N_EDGES * 4);
  int*      csr     = (int*)alloc((size_t)N_EDGES * 4);
  int*      offs    = (int*)alloc((size_t)(N_NODES + 1) * 4);
  int*      boffs   = (int*)alloc((size_t)(NB + 1) * 4);
  int*      bcursor = (int*)alloc((size_t)NB * 4);
  int*      goff    = (int*)alloc((size_t)(N_GRAPHS + 1) * 4);
  float*    pooled  = (float*)alloc((size_t)N_GRAPHS * ITERS * DDIM * 4);
  float*    colsum  = (float*)alloc(128 * 4);
  bf16x8*   wbuf    = (bf16x8*)alloc((size_t)48 * 64 * 16);   // hi + lo fragments
  float*    partial = (float*)alloc((size_t)128 * PPITCH * 4);
  // contiguous zero region: bhist | gcnt
  size_t zbytes = (size_t)NB * 4 + (size_t)N_GRAPHS * 4;
  char*  zbase  = alloc(zbytes);
  int*   bhist  = (int*)zbase;
  int*   gcnt   = bhist + NB;

  hipMemsetAsync(zbase, 0, zbytes, stream);

  embed_kernel<<<(N_NODES * 16 + 255) / 256, 256, 0, stream>>>(pkt, (const float4*)emb,
                                                               (bf16x4*)hb);
  bucket_hist_kernel<<<512, 256, 0, stream>>>(dst, bhist);
  hist_kernel<<<(N_NODES + 255) / 256, 256, 0, stream>>>(gids, gcnt, N_NODES);
  scan_kernel<<<1, 1024, 0, stream>>>(bhist, boffs, bcursor, NB);
  scan_kernel<<<1, 1024, 0, stream>>>(gcnt, goff, nullptr, N_GRAPHS);
  partition_kernel<<<NPB, 256, 0, stream>>>(src, dst, bcursor, ebuf);
  local_scatter_kernel<<<NB, 256, 0, stream>>>(ebuf, boffs, offs, csr);
  pack_weights_kernel<<<6, 256, 0, stream>>>(W1, W2, W3, wbuf);

  for (int it = 0; it < ITERS; ++it) {
    aggregate_kernel<<<(N_NODES + 3) / 4, 256, 0, stream>>>(hb, offs, csr, eps, x);
    mlp_kernel<<<NB, 256, 0, stream>>>(x, x, wbuf, b1, b2, b3, partial);
    bn_stats_kernel<<<32, 256, 0, stream>>>(partial, colsum);
    norm_pool_kernel<<<N_GRAPHS, 256, 0, stream>>>(x, hb, pooled, goff, colsum, gamma, beta, it);
  }
  classifier_kernel<<<N_GRAPHS, 64, 0, stream>>>(pooled, Wc, bc, out);
}